// Round 1
// baseline (229.463 us; speedup 1.0000x reference)
//
#include <hip/hip_runtime.h>
#include <hip/hip_bf16.h>
#include <math.h>

#define D_MODEL 1024
#define N_HEADS 16
#define D_K     64
#define S_LEN   2048
#define B_SZ    2

typedef unsigned short u16;
typedef unsigned int   u32;
using short8 = __attribute__((ext_vector_type(8))) short;
using f32x4  = __attribute__((ext_vector_type(4))) float;

__device__ inline float bf2f(u16 u) { return __uint_as_float((u32)u << 16); }
__device__ inline u16 f2bf(float f) {
    __hip_bfloat16 h = __float2bfloat16(f);   // RNE
    return *(u16*)&h;
}
__device__ inline void gload_lds16(const void* g, void* l) {
    __builtin_amdgcn_global_load_lds(
        (const __attribute__((address_space(1))) unsigned int*)g,
        (__attribute__((address_space(3))) unsigned int*)l, 16, 0, 0);
}

// ---------------------------------------------------------------------------
// fp32 -> bf16 cast for all three inputs in ONE launch (x | W_qkv | W_out).
// ---------------------------------------------------------------------------
__global__ __launch_bounds__(256)
void cast3_f32_bf16(const float* __restrict__ a, u16* __restrict__ ao, int na4,
                    const float* __restrict__ bsrc, u16* __restrict__ bo, int nb4,
                    const float* __restrict__ c, u16* __restrict__ co, int nc4) {
    int j = blockIdx.x * 256 + threadIdx.x;
    const float* src; u16* dst;
    if (j < na4) { src = a; dst = ao; }
    else {
        j -= na4;
        if (j < nb4) { src = bsrc; dst = bo; }
        else {
            j -= nb4;
            if (j >= nc4) return;
            src = c; dst = co;
        }
    }
    float4 v = ((const float4*)src)[j];
    ushort4 u;
    u.x = f2bf(v.x); u.y = f2bf(v.y); u.z = f2bf(v.z); u.w = f2bf(v.w);
    ((ushort4*)dst)[j] = u;
}

// ---------------------------------------------------------------------------
// bf16 MFMA GEMM (m97 structure): C[M][N] = A[M][K] * B[N][K]^T.  (verified)
// ---------------------------------------------------------------------------
template <bool OUT_BF16>
__global__ __launch_bounds__(256)
void gemm_bt_mfma(const u16* __restrict__ A, const u16* __restrict__ B,
                  void* __restrict__ Cout, int M, int N, int K) {
    __shared__ u16 As[128 * 32];
    __shared__ u16 Bs[128 * 32];
    const int tid  = threadIdx.x;
    const int lane = tid & 63;
    const int wv   = tid >> 6;
    const int wm   = wv >> 1, wn = wv & 1;
    const int row0 = blockIdx.y * 128;
    const int col0 = blockIdx.x * 128;

    const int lr = lane >> 2;
    const int lc = (lane & 3) * 8;

    f32x4 acc[4][4] = {};

    for (int k0 = 0; k0 < K; k0 += 32) {
#pragma unroll
        for (int t = 0; t < 2; t++) {
            int rblk = wv * 32 + t * 16;
            gload_lds16(A + (size_t)(row0 + rblk + lr) * K + k0 + lc, &As[rblk * 32]);
            gload_lds16(B + (size_t)(col0 + rblk + lr) * K + k0 + lc, &Bs[rblk * 32]);
        }
        __syncthreads();

        short8 af[4], bfr[4];
#pragma unroll
        for (int mi = 0; mi < 4; mi++)
            af[mi] = *(const short8*)&As[(wm * 64 + mi * 16 + (lane & 15)) * 32 + (lane >> 4) * 8];
#pragma unroll
        for (int nj = 0; nj < 4; nj++)
            bfr[nj] = *(const short8*)&Bs[(wn * 64 + nj * 16 + (lane & 15)) * 32 + (lane >> 4) * 8];
#pragma unroll
        for (int mi = 0; mi < 4; mi++)
#pragma unroll
            for (int nj = 0; nj < 4; nj++)
                acc[mi][nj] = __builtin_amdgcn_mfma_f32_16x16x32_bf16(
                    af[mi], bfr[nj], acc[mi][nj], 0, 0, 0);
        __syncthreads();
    }

    const int cr = (lane >> 4) * 4;
    const int cc = lane & 15;
#pragma unroll
    for (int mi = 0; mi < 4; mi++) {
#pragma unroll
        for (int nj = 0; nj < 4; nj++) {
            int c = col0 + wn * 64 + nj * 16 + cc;
#pragma unroll
            for (int r = 0; r < 4; r++) {
                int rr = row0 + wm * 64 + mi * 16 + cr + r;
                if (OUT_BF16)
                    ((u16*)Cout)[(size_t)rr * N + c] = f2bf(acc[mi][nj][r]);
                else
                    ((float*)Cout)[(size_t)rr * N + c] = acc[mi][nj][r];
            }
        }
    }
}

// ---------------------------------------------------------------------------
// RoPE in place on bf16 qkv (Q and K slices); Q additionally scaled by
// 1/sqrt(d_k).
// ---------------------------------------------------------------------------
__global__ __launch_bounds__(256)
void rope_bf16(u16* __restrict__ qkv, const int* __restrict__ pos) {
    int idx = blockIdx.x * blockDim.x + threadIdx.x;
    int j = idx & 31;
    int h = (idx >> 5) & 15;
    int w = (idx >> 9) & 1;
    int s = (idx >> 10) & 2047;
    int b = idx >> 21;

    float p = (float)pos[s];
    float inv_freq = __powf(10000.0f, -(float)(2 * j) / 64.0f);
    float ang = p * inv_freq;
    float sn, cs;
    sincosf(ang, &sn, &cs);
    float sc = (w == 0) ? 0.125f : 1.0f;

    size_t base = (((size_t)(b * S_LEN + s) * 3 + w) * D_MODEL) + h * D_K + 2 * j;
    float x1 = bf2f(qkv[base]);
    float x2 = bf2f(qkv[base + 1]);
    qkv[base]     = f2bf((x1 * cs - x2 * sn) * sc);
    qkv[base + 1] = f2bf((x1 * sn + x2 * cs) * sc);
}

// ---------------------------------------------------------------------------
// V transpose: qkv V slice (B,S,3,H,D) -> VT (B,H,D,S). 64x64 LDS tile.
// ---------------------------------------------------------------------------
__global__ __launch_bounds__(256)
void vtrans(const u16* __restrict__ qkv, u16* __restrict__ VT) {
    __shared__ u16 t[64][68];
    const int st = blockIdx.x, h = blockIdx.y, b = blockIdx.z;
    const int tid = threadIdx.x;
    const int bh = b * N_HEADS + h;

#pragma unroll
    for (int i = 0; i < 4; i++) {
        int e  = tid + i * 256;
        int sl = e >> 4;
        int c4 = e & 15;
        ushort4 v = *(const ushort4*)&qkv[((size_t)(b * S_LEN + st * 64 + sl) * 3 + 2) * D_MODEL
                                          + h * D_K + c4 * 4];
        *(ushort4*)&t[sl][c4 * 4] = v;
    }
    __syncthreads();
#pragma unroll
    for (int i = 0; i < 4; i++) {
        int e  = tid + i * 256;
        int d  = e >> 4;
        int s4 = e & 15;
        ushort4 o;
        o.x = t[s4 * 4 + 0][d];
        o.y = t[s4 * 4 + 1][d];
        o.z = t[s4 * 4 + 2][d];
        o.w = t[s4 * 4 + 3][d];
        *(ushort4*)&VT[((size_t)bh * D_K + d) * S_LEN + st * 64 + s4 * 4] = o;
    }
}

// ---------------------------------------------------------------------------
// MFMA flash attention v3 (causal), S^T formulation.
//
// Changes vs v2 (the 249 us version):
//  * T3-minimal 2-phase pipeline: K/V tiles are DOUBLE-BUFFERED in LDS and
//    tile kt+1 is staged (global_load_lds, async) BEFORE computing tile kt.
//    One __syncthreads per iteration (its vmcnt(0)+lgkmcnt(0) drain both
//    retires the prefetch and fences the buffer swap) instead of two.
//    Global-load latency now hides under QK^T + softmax + PV.
//  * T1 XCD pinning: 1D grid; all 32 q-tile blocks of one (b,h) share
//    bid&7, i.e. one XCD under round-robin dispatch -> that head's 512 KB
//    K/V stays resident in ONE 4 MiB L2 (4 heads/XCD = 2 MiB working set)
//    instead of being replicated 8x and spilling to HBM. qt reversed so
//    longest blocks launch first.
//  * T5: s_setprio(1) around both MFMA clusters (+4-7% measured on attn).
//
// Block = 4 waves per (b, h, 64-query tile); wave w owns queries w*16..+15.
// S^T = K*Q^T (A=K, B=Q) -> C-layout: row=key=quad*4+r, col=query=l15:
// one query per lane -> softmax reductions are 15 in-lane fmax + 2 shfl_xor.
// P: packed bf16-pair b64 stores into a wave-private [query][key] LDS strip
// (row stride 68 u16), no barrier. PV: A=P (m=query), B=VsT (n=d).
// ---------------------------------------------------------------------------
__global__ __launch_bounds__(256)
void attn_mfma(const u16* __restrict__ qkv, const u16* __restrict__ VT,
               u16* __restrict__ out) {
    __shared__ u16 Ks[2][2][64 * 32];    // [buf][kf d-chunk][key*32 + dL]
    __shared__ u16 VsT[2][2][64 * 32];   // [buf][kc key-chunk][d*32 + kL]
    __shared__ u16 Ps[4][16 * 68];       // per-wave [query 16][key 64 + pad 4]

    const int tid  = threadIdx.x;
    const int lane = tid & 63;
    const int wv   = tid >> 6;

    // XCD-pinned decode (bijective over bid 0..1023):
    //   xcd = bid&7, idx = bid>>3; bh = xcd*4 + idx>>5; qt = 31 - (idx&31).
    const int bid = blockIdx.x;
    const int idx = bid >> 3;
    const int bh  = (bid & 7) * 4 + (idx >> 5);
    const int qt  = 31 - (idx & 31);               // longest blocks first
    const int h   = bh & (N_HEADS - 1);
    const int b   = bh >> 4;

    const int q0   = qt * 64;
    const int qw0  = q0 + wv * 16;                 // this wave's first query
    const int l15  = lane & 15;
    const int quad = lane >> 4;

    const size_t vtb = (size_t)bh * D_K * S_LEN;
    u16* Psw = &Ps[wv][0];

    const int lr = lane >> 2;
    const int lc = (lane & 3) * 8;

    // Q fragments (B-operand layout [n=query l15][k=d quad*8+j]); Q pre-scaled.
    short8 qf[2];
#pragma unroll
    for (int kf = 0; kf < 2; kf++)
        qf[kf] = *(const short8*)&qkv[((size_t)(b * S_LEN + qw0 + l15) * 3 + 0) * D_MODEL
                                      + h * D_K + kf * 32 + quad * 8];

    f32x4 acc[4] = {};          // O: row=query quad*4+r, col=d nj*16+l15
    float mq = -INFINITY;       // per-lane stats for query l15 (replicated per quad)
    float lq = 0.f;

    // async-stage K/V tile kts into LDS buffer bf (wave-uniform LDS base,
    // lane-linear dest -- the gload_lds contract).
    auto STAGE = [&](int kts, int bf) {
        const int k0s = kts * 64;
#pragma unroll
        for (int kf = 0; kf < 2; kf++)
            gload_lds16(qkv + ((size_t)(b * S_LEN + k0s + wv * 16 + lr) * 3 + 1) * D_MODEL
                            + h * D_K + kf * 32 + lc,
                        &Ks[bf][kf][(wv * 16) * 32]);
#pragma unroll
        for (int kc = 0; kc < 2; kc++)
            gload_lds16(VT + vtb + (size_t)(wv * 16 + lr) * S_LEN + k0s + kc * 32 + lc,
                        &VsT[bf][kc][(wv * 16) * 32]);
    };

    STAGE(0, 0);
    __syncthreads();            // vmcnt(0) drain -> tile 0 resident

    int cur = 0;
    for (int kt = 0; kt <= qt; kt++) {
        const int k0 = kt * 64;

        // prefetch next tile into the other buffer; latency hides under
        // this iteration's compute, retired by the end-of-iter barrier.
        if (kt < qt) STAGE(kt + 1, cur ^ 1);

        // ---- S^T = K*Q^T : s[nj] rows=keys nj*16+quad*4+r, col=query l15 ----
        f32x4 s[4] = {};
        __builtin_amdgcn_s_setprio(1);
#pragma unroll
        for (int kf = 0; kf < 2; kf++)
#pragma unroll
            for (int nj = 0; nj < 4; nj++) {
                short8 kfr = *(const short8*)&Ks[cur][kf][(nj * 16 + l15) * 32 + quad * 8];
                s[nj] = __builtin_amdgcn_mfma_f32_16x16x32_bf16(kfr, qf[kf], s[nj], 0, 0, 0);
            }
        __builtin_amdgcn_s_setprio(0);

        // ---- causal mask (diagonal tile only) ----
        if (k0 + 63 > qw0) {
            const int row_g = qw0 + l15;
#pragma unroll
            for (int nj = 0; nj < 4; nj++)
#pragma unroll
                for (int r = 0; r < 4; r++) {
                    int key_g = k0 + nj * 16 + quad * 4 + r;
                    if (key_g > row_g) s[nj][r] = -INFINITY;
                }
        }

        // ---- online softmax: one query per lane, 16 keys in-lane ----
        float rmax = s[0][0];
#pragma unroll
        for (int nj = 0; nj < 4; nj++)
#pragma unroll
            for (int r = 0; r < 4; r++) rmax = fmaxf(rmax, s[nj][r]);
        rmax = fmaxf(rmax, __shfl_xor(rmax, 16, 64));
        rmax = fmaxf(rmax, __shfl_xor(rmax, 32, 64));
        float mn = fmaxf(mq, rmax);
        float alpha = __expf(mq - mn);
        mq = mn;
        float rsum = 0.f;
#pragma unroll
        for (int nj = 0; nj < 4; nj++)
#pragma unroll
            for (int r = 0; r < 4; r++) {
                float p = __expf(s[nj][r] - mn);
                s[nj][r] = p;
                rsum += p;
            }
        rsum += __shfl_xor(rsum, 16, 64);
        rsum += __shfl_xor(rsum, 32, 64);
        lq = lq * alpha + rsum;

        // ---- rescale O: alpha lives at lane l15=query; O rows are quad*4+r ----
#pragma unroll
        for (int r = 0; r < 4; r++) {
            float ar = __shfl(alpha, quad * 4 + r, 64);
#pragma unroll
            for (int nj = 0; nj < 4; nj++) acc[nj][r] *= ar;
        }

        // ---- P (bf16 pairs) -> wave-private LDS strip [query][key] ----
#pragma unroll
        for (int nj = 0; nj < 4; nj++) {
            u32 lo = ((u32)f2bf(s[nj][1]) << 16) | f2bf(s[nj][0]);
            u32 hi = ((u32)f2bf(s[nj][3]) << 16) | f2bf(s[nj][2]);
            uint2 pk; pk.x = lo; pk.y = hi;
            *(uint2*)&Psw[l15 * 68 + nj * 16 + quad * 4] = pk;
        }
        // same-wave LDS RAW -> compiler inserts lgkmcnt wait

        // ---- O += P*V : A=P[m=query][k=key], B=VsT[n=d][k=key] ----
        __builtin_amdgcn_s_setprio(1);
#pragma unroll
        for (int kf = 0; kf < 2; kf++) {
            const u16* pp = &Psw[l15 * 68 + kf * 32 + quad * 8];
            uint2 plo = *(const uint2*)pp;
            uint2 phi = *(const uint2*)(pp + 4);
            u32 praw[4] = { plo.x, plo.y, phi.x, phi.y };
            short8 pf = *(const short8*)praw;
#pragma unroll
            for (int nj = 0; nj < 4; nj++) {
                short8 vf = *(const short8*)&VsT[cur][kf][(nj * 16 + l15) * 32 + quad * 8];
                acc[nj] = __builtin_amdgcn_mfma_f32_16x16x32_bf16(pf, vf, acc[nj], 0, 0, 0);
            }
        }
        __builtin_amdgcn_s_setprio(0);

        // retire prefetch (vmcnt 0) + fence buffer swap, one barrier/iter
        __syncthreads();
        cur ^= 1;
    }

    // ---- epilogue: normalize (invl per query), store bf16 (B,S,H*D) ----
    float invl = 1.f / lq;
#pragma unroll
    for (int r = 0; r < 4; r++) {
        float ir = __shfl(invl, quad * 4 + r, 64);
        int row_g = qw0 + quad * 4 + r;
#pragma unroll
        for (int nj = 0; nj < 4; nj++)
            out[(size_t)(b * S_LEN + row_g) * D_MODEL + h * D_K + nj * 16 + l15] =
                f2bf(acc[nj][r] * ir);
    }
}

// ---------------------------------------------------------------------------
extern "C" void kernel_launch(void* const* d_in, const int* in_sizes, int n_in,
                              void* d_out, int out_size, void* d_ws, size_t ws_size,
                              hipStream_t stream) {
    const float* x    = (const float*)d_in[0];
    const int*   pos  = (const int*)d_in[1];
    const float* Wqkv = (const float*)d_in[2];
    const float* Wout = (const float*)d_in[3];
    float*       out  = (float*)d_out;

    const int M = B_SZ * S_LEN;   // 4096

    u16* qkvb = (u16*)d_ws;                            // 4096 x 3072
    u16* aob  = qkvb + (size_t)M * 3 * D_MODEL;        // 4096 x 1024
    u16* xb   = aob  + (size_t)M * D_MODEL;            // 4096 x 1024
    u16* wqb  = xb   + (size_t)M * D_MODEL;            // 3072 x 1024
    u16* wob  = wqb  + (size_t)3 * D_MODEL * D_MODEL;  // 1024 x 1024
    u16* vtb  = wob  + (size_t)D_MODEL * D_MODEL;      // 4096 x 1024

    const int na4 = M * D_MODEL / 4;
    const int nb4 = 3 * D_MODEL * D_MODEL / 4;
    const int nc4 = D_MODEL * D_MODEL / 4;
    cast3_f32_bf16<<<(na4 + nb4 + nc4 + 255) / 256, 256, 0, stream>>>(
        x, xb, na4, Wqkv, wqb, nb4, Wout, wob, nc4);

    gemm_bt_mfma<true><<<dim3(3 * D_MODEL / 128, M / 128), 256, 0, stream>>>(
        xb, wqb, qkvb, M, 3 * D_MODEL, D_MODEL);

    rope_bf16<<<(B_SZ * S_LEN * 2 * N_HEADS * 32) / 256, 256, 0, stream>>>(qkvb, pos);

    vtrans<<<dim3(S_LEN / 64, N_HEADS, B_SZ), 256, 0, stream>>>(qkvb, vtb);

    attn_mfma<<<(S_LEN / 64) * N_HEADS * B_SZ, 256, 0, stream>>>(qkvb, vtb, aob);

    gemm_bt_mfma<false><<<dim3(D_MODEL / 128, M / 128), 256, 0, stream>>>(
        aob, wob, out, M, D_MODEL, D_MODEL);
}

// Round 2
// 222.350 us; speedup vs baseline: 1.0320x; 1.0320x over previous
//
#include <hip/hip_runtime.h>
#include <hip/hip_bf16.h>
#include <math.h>

#define D_MODEL 1024
#define N_HEADS 16
#define D_K     64
#define S_LEN   2048
#define B_SZ    2

typedef unsigned short u16;
typedef unsigned int   u32;
using short8 = __attribute__((ext_vector_type(8))) short;
using f32x4  = __attribute__((ext_vector_type(4))) float;

__device__ inline float bf2f(u16 u) { return __uint_as_float((u32)u << 16); }
__device__ inline u16 f2bf(float f) {
    __hip_bfloat16 h = __float2bfloat16(f);   // RNE
    return *(u16*)&h;
}
__device__ inline void gload_lds16(const void* g, void* l) {
    __builtin_amdgcn_global_load_lds(
        (const __attribute__((address_space(1))) unsigned int*)g,
        (__attribute__((address_space(3))) unsigned int*)l, 16, 0, 0);
}

// ---------------------------------------------------------------------------
// fp32 -> bf16 cast for all three inputs in ONE launch (x | W_qkv | W_out).
// ---------------------------------------------------------------------------
__global__ __launch_bounds__(256)
void cast3_f32_bf16(const float* __restrict__ a, u16* __restrict__ ao, int na4,
                    const float* __restrict__ bsrc, u16* __restrict__ bo, int nb4,
                    const float* __restrict__ c, u16* __restrict__ co, int nc4) {
    int j = blockIdx.x * 256 + threadIdx.x;
    const float* src; u16* dst;
    if (j < na4) { src = a; dst = ao; }
    else {
        j -= na4;
        if (j < nb4) { src = bsrc; dst = bo; }
        else {
            j -= nb4;
            if (j >= nc4) return;
            src = c; dst = co;
        }
    }
    float4 v = ((const float4*)src)[j];
    ushort4 u;
    u.x = f2bf(v.x); u.y = f2bf(v.y); u.z = f2bf(v.z); u.w = f2bf(v.w);
    ((ushort4*)dst)[j] = u;
}

// ---------------------------------------------------------------------------
// bf16 MFMA GEMM (m97 structure): C[M][N] = A[M][K] * B[N][K]^T.  (verified)
// ---------------------------------------------------------------------------
template <bool OUT_BF16>
__global__ __launch_bounds__(256)
void gemm_bt_mfma(const u16* __restrict__ A, const u16* __restrict__ B,
                  void* __restrict__ Cout, int M, int N, int K) {
    __shared__ u16 As[128 * 32];
    __shared__ u16 Bs[128 * 32];
    const int tid  = threadIdx.x;
    const int lane = tid & 63;
    const int wv   = tid >> 6;
    const int wm   = wv >> 1, wn = wv & 1;
    const int row0 = blockIdx.y * 128;
    const int col0 = blockIdx.x * 128;

    const int lr = lane >> 2;
    const int lc = (lane & 3) * 8;

    f32x4 acc[4][4] = {};

    for (int k0 = 0; k0 < K; k0 += 32) {
#pragma unroll
        for (int t = 0; t < 2; t++) {
            int rblk = wv * 32 + t * 16;
            gload_lds16(A + (size_t)(row0 + rblk + lr) * K + k0 + lc, &As[rblk * 32]);
            gload_lds16(B + (size_t)(col0 + rblk + lr) * K + k0 + lc, &Bs[rblk * 32]);
        }
        __syncthreads();

        short8 af[4], bfr[4];
#pragma unroll
        for (int mi = 0; mi < 4; mi++)
            af[mi] = *(const short8*)&As[(wm * 64 + mi * 16 + (lane & 15)) * 32 + (lane >> 4) * 8];
#pragma unroll
        for (int nj = 0; nj < 4; nj++)
            bfr[nj] = *(const short8*)&Bs[(wn * 64 + nj * 16 + (lane & 15)) * 32 + (lane >> 4) * 8];
#pragma unroll
        for (int mi = 0; mi < 4; mi++)
#pragma unroll
            for (int nj = 0; nj < 4; nj++)
                acc[mi][nj] = __builtin_amdgcn_mfma_f32_16x16x32_bf16(
                    af[mi], bfr[nj], acc[mi][nj], 0, 0, 0);
        __syncthreads();
    }

    const int cr = (lane >> 4) * 4;
    const int cc = lane & 15;
#pragma unroll
    for (int mi = 0; mi < 4; mi++) {
#pragma unroll
        for (int nj = 0; nj < 4; nj++) {
            int c = col0 + wn * 64 + nj * 16 + cc;
#pragma unroll
            for (int r = 0; r < 4; r++) {
                int rr = row0 + wm * 64 + mi * 16 + cr + r;
                if (OUT_BF16)
                    ((u16*)Cout)[(size_t)rr * N + c] = f2bf(acc[mi][nj][r]);
                else
                    ((float*)Cout)[(size_t)rr * N + c] = acc[mi][nj][r];
            }
        }
    }
}

// ---------------------------------------------------------------------------
// RoPE in place on bf16 qkv (Q and K slices); Q additionally scaled by
// 1/sqrt(d_k).
// ---------------------------------------------------------------------------
__global__ __launch_bounds__(256)
void rope_bf16(u16* __restrict__ qkv, const int* __restrict__ pos) {
    int idx = blockIdx.x * blockDim.x + threadIdx.x;
    int j = idx & 31;
    int h = (idx >> 5) & 15;
    int w = (idx >> 9) & 1;
    int s = (idx >> 10) & 2047;
    int b = idx >> 21;

    float p = (float)pos[s];
    float inv_freq = __powf(10000.0f, -(float)(2 * j) / 64.0f);
    float ang = p * inv_freq;
    float sn, cs;
    sincosf(ang, &sn, &cs);
    float sc = (w == 0) ? 0.125f : 1.0f;

    size_t base = (((size_t)(b * S_LEN + s) * 3 + w) * D_MODEL) + h * D_K + 2 * j;
    float x1 = bf2f(qkv[base]);
    float x2 = bf2f(qkv[base + 1]);
    qkv[base]     = f2bf((x1 * cs - x2 * sn) * sc);
    qkv[base + 1] = f2bf((x1 * sn + x2 * cs) * sc);
}

// ---------------------------------------------------------------------------
// V transpose: qkv V slice (B,S,3,H,D) -> VT (B,H,D,S). 64x64 LDS tile.
// ---------------------------------------------------------------------------
__global__ __launch_bounds__(256)
void vtrans(const u16* __restrict__ qkv, u16* __restrict__ VT) {
    __shared__ u16 t[64][68];
    const int st = blockIdx.x, h = blockIdx.y, b = blockIdx.z;
    const int tid = threadIdx.x;
    const int bh = b * N_HEADS + h;

#pragma unroll
    for (int i = 0; i < 4; i++) {
        int e  = tid + i * 256;
        int sl = e >> 4;
        int c4 = e & 15;
        ushort4 v = *(const ushort4*)&qkv[((size_t)(b * S_LEN + st * 64 + sl) * 3 + 2) * D_MODEL
                                          + h * D_K + c4 * 4];
        *(ushort4*)&t[sl][c4 * 4] = v;
    }
    __syncthreads();
#pragma unroll
    for (int i = 0; i < 4; i++) {
        int e  = tid + i * 256;
        int d  = e >> 4;
        int s4 = e & 15;
        ushort4 o;
        o.x = t[s4 * 4 + 0][d];
        o.y = t[s4 * 4 + 1][d];
        o.z = t[s4 * 4 + 2][d];
        o.w = t[s4 * 4 + 3][d];
        *(ushort4*)&VT[((size_t)bh * D_K + d) * S_LEN + st * 64 + s4 * 4] = o;
    }
}

// ---------------------------------------------------------------------------
// One attention step for one 16-query wave-tile against the 64-key tile
// currently resident in LDS (Ksc/Vsc point at buffer [cur]).
// S^T = K*Q^T (A=K, B=Q) -> C-layout: row=key=quad*4+r, col=query=l15.
// Online softmax per lane (one query), P round-trips through a private
// LDS strip to reach the PV A-operand layout, O accumulates in registers.
// ---------------------------------------------------------------------------
__device__ __forceinline__ void attn_step(
    const u16* __restrict__ Ksc, const u16* __restrict__ Vsc,
    u16* __restrict__ Psw,
    short8 (&qf)[2], f32x4 (&acc)[4], float& mq, float& lq,
    int k0, int qw0, bool diag, int l15, int quad)
{
    // ---- S^T = K*Q^T ----
    f32x4 s[4] = {};
    __builtin_amdgcn_s_setprio(1);
#pragma unroll
    for (int kf = 0; kf < 2; kf++)
#pragma unroll
        for (int nj = 0; nj < 4; nj++) {
            short8 kfr = *(const short8*)&Ksc[kf * 2048 + (nj * 16 + l15) * 32 + quad * 8];
            s[nj] = __builtin_amdgcn_mfma_f32_16x16x32_bf16(kfr, qf[kf], s[nj], 0, 0, 0);
        }
    __builtin_amdgcn_s_setprio(0);

    // ---- causal mask (diagonal tile only) ----
    if (diag) {
        const int row_g = qw0 + l15;
#pragma unroll
        for (int nj = 0; nj < 4; nj++)
#pragma unroll
            for (int r = 0; r < 4; r++) {
                int key_g = k0 + nj * 16 + quad * 4 + r;
                if (key_g > row_g) s[nj][r] = -INFINITY;
            }
    }

    // ---- online softmax: one query per lane, 16 keys in-lane ----
    float rmax = s[0][0];
#pragma unroll
    for (int nj = 0; nj < 4; nj++)
#pragma unroll
        for (int r = 0; r < 4; r++) rmax = fmaxf(rmax, s[nj][r]);
    rmax = fmaxf(rmax, __shfl_xor(rmax, 16, 64));
    rmax = fmaxf(rmax, __shfl_xor(rmax, 32, 64));
    float mn = fmaxf(mq, rmax);
    float alpha = __expf(mq - mn);
    mq = mn;
    float rsum = 0.f;
#pragma unroll
    for (int nj = 0; nj < 4; nj++)
#pragma unroll
        for (int r = 0; r < 4; r++) {
            float p = __expf(s[nj][r] - mn);
            s[nj][r] = p;
            rsum += p;
        }
    rsum += __shfl_xor(rsum, 16, 64);
    rsum += __shfl_xor(rsum, 32, 64);
    lq = lq * alpha + rsum;

    // ---- rescale O: alpha lives at lane l15=query; O rows are quad*4+r ----
#pragma unroll
    for (int r = 0; r < 4; r++) {
        float ar = __shfl(alpha, quad * 4 + r, 64);
#pragma unroll
        for (int nj = 0; nj < 4; nj++) acc[nj][r] *= ar;
    }

    // ---- P (bf16 pairs) -> wave-private LDS strip [query][key] ----
#pragma unroll
    for (int nj = 0; nj < 4; nj++) {
        u32 lo = ((u32)f2bf(s[nj][1]) << 16) | f2bf(s[nj][0]);
        u32 hi = ((u32)f2bf(s[nj][3]) << 16) | f2bf(s[nj][2]);
        uint2 pk; pk.x = lo; pk.y = hi;
        *(uint2*)&Psw[l15 * 68 + nj * 16 + quad * 4] = pk;
    }
    // same-wave LDS RAW -> compiler inserts lgkmcnt wait

    // ---- O += P*V : A=P[m=query][k=key], B=VsT[n=d][k=key] ----
    __builtin_amdgcn_s_setprio(1);
#pragma unroll
    for (int kf = 0; kf < 2; kf++) {
        const u16* pp = &Psw[l15 * 68 + kf * 32 + quad * 8];
        uint2 plo = *(const uint2*)pp;
        uint2 phi = *(const uint2*)(pp + 4);
        u32 praw[4] = { plo.x, plo.y, phi.x, phi.y };
        short8 pf = *(const short8*)praw;
#pragma unroll
        for (int nj = 0; nj < 4; nj++) {
            short8 vf = *(const short8*)&Vsc[kf * 2048 + (nj * 16 + l15) * 32 + quad * 8];
            acc[nj] = __builtin_amdgcn_mfma_f32_16x16x32_bf16(pf, vf, acc[nj], 0, 0, 0);
        }
    }
    __builtin_amdgcn_s_setprio(0);
}

// ---------------------------------------------------------------------------
// MFMA flash attention v4 (causal), S^T formulation, PAIRED q-tiles.
//
// Changes vs v3 (67.5 us dispatch, MfmaUtil 10%, Occupancy 19%):
//  * Causal load-balance pairing: ONE block owns q-tiles {pr, 31-pr}.
//    Every block does exactly (32-pr) + (pr+1) = 33 tile-computes -> no
//    tail (v3's blocks ranged 1..32 K-tiles; short blocks retired early
//    and CUs idled at time-avg occupancy 19%).
//  * The short tile's key range is a PREFIX of the long tile's -> one
//    shared K/V staging loop serves both (staging + barrier count per
//    (b,h) drops 528 -> 392), and the two tiles' compute chains are
//    independent -> ILP across hi-softmax / lo-MFMA.
//  * Grid 512, XCD pinning kept: 16 pair-blocks x 4 bh per XCD (~2 MiB
//    resident KV per 4 MiB L2), exactly 2 blocks/CU, all equal length.
//  * 2-phase K/V double-buffer + prefetch-before-compute + setprio kept.
// ---------------------------------------------------------------------------
__global__ __launch_bounds__(256)
void attn_mfma(const u16* __restrict__ qkv, const u16* __restrict__ VT,
               u16* __restrict__ out) {
    __shared__ u16 Ks[2][2][64 * 32];    // [buf][kf d-chunk][key*32 + dL]
    __shared__ u16 VsT[2][2][64 * 32];   // [buf][kc key-chunk][d*32 + kL]
    __shared__ u16 Ps[2][4][16 * 68];    // [tile][wave][query 16][key 64 + pad]

    const int tid  = threadIdx.x;
    const int lane = tid & 63;
    const int wv   = tid >> 6;

    // XCD-pinned paired decode (bijective over bid 0..511):
    //   xcd = bid&7; idx = bid>>3; bh = xcd*4 + (idx>>4); pr = idx&15;
    //   q-tiles qtH = 31-pr (long) and qtL = pr (short).
    const int bid = blockIdx.x;
    const int idx = bid >> 3;
    const int bh  = (bid & 7) * 4 + (idx >> 4);
    const int pr  = idx & 15;
    const int qtH = 31 - pr;
    const int qtL = pr;
    const int h   = bh & (N_HEADS - 1);
    const int b   = bh >> 4;

    const int l15  = lane & 15;
    const int quad = lane >> 4;
    const int qw0H = qtH * 64 + wv * 16;
    const int qw0L = qtL * 64 + wv * 16;

    const size_t vtb = (size_t)bh * D_K * S_LEN;
    u16* PswH = &Ps[0][wv][0];
    u16* PswL = &Ps[1][wv][0];

    const int lr = lane >> 2;
    const int lc = (lane & 3) * 8;

    // Q fragments (B-operand layout [n=query l15][k=d quad*8+j]); Q pre-scaled.
    short8 qfH[2], qfL[2];
#pragma unroll
    for (int kf = 0; kf < 2; kf++) {
        qfH[kf] = *(const short8*)&qkv[((size_t)(b * S_LEN + qw0H + l15) * 3 + 0) * D_MODEL
                                       + h * D_K + kf * 32 + quad * 8];
        qfL[kf] = *(const short8*)&qkv[((size_t)(b * S_LEN + qw0L + l15) * 3 + 0) * D_MODEL
                                       + h * D_K + kf * 32 + quad * 8];
    }

    f32x4 accH[4] = {}, accL[4] = {};
    float mqH = -INFINITY, lqH = 0.f;
    float mqL = -INFINITY, lqL = 0.f;

    // async-stage K/V tile kts into LDS buffer bf (wave-uniform LDS base,
    // lane-linear dest -- the gload_lds contract).
    auto STAGE = [&](int kts, int bf) {
        const int k0s = kts * 64;
#pragma unroll
        for (int kf = 0; kf < 2; kf++)
            gload_lds16(qkv + ((size_t)(b * S_LEN + k0s + wv * 16 + lr) * 3 + 1) * D_MODEL
                            + h * D_K + kf * 32 + lc,
                        &Ks[bf][kf][(wv * 16) * 32]);
#pragma unroll
        for (int kc = 0; kc < 2; kc++)
            gload_lds16(VT + vtb + (size_t)(wv * 16 + lr) * S_LEN + k0s + kc * 32 + lc,
                        &VsT[bf][kc][(wv * 16) * 32]);
    };

    STAGE(0, 0);
    __syncthreads();            // vmcnt(0) drain -> tile 0 resident

    int cur = 0;
    for (int kt = 0; kt <= qtH; kt++) {
        const int k0 = kt * 64;

        // prefetch next tile into the other buffer; latency hides under
        // this iteration's compute, retired by the end-of-iter barrier.
        if (kt < qtH) STAGE(kt + 1, cur ^ 1);

        const u16* Ksc = &Ks[cur][0][0];
        const u16* Vsc = &VsT[cur][0][0];

        attn_step(Ksc, Vsc, PswH, qfH, accH, mqH, lqH,
                  k0, qw0H, kt == qtH, l15, quad);
        if (kt <= qtL)
            attn_step(Ksc, Vsc, PswL, qfL, accL, mqL, lqL,
                      k0, qw0L, kt == qtL, l15, quad);

        // retire prefetch (vmcnt 0) + fence buffer swap, one barrier/iter
        __syncthreads();
        cur ^= 1;
    }

    // ---- epilogue: normalize (invl per query), store bf16 (B,S,H*D) ----
    float invlH = 1.f / lqH;
    float invlL = 1.f / lqL;
#pragma unroll
    for (int r = 0; r < 4; r++) {
        float irH = __shfl(invlH, quad * 4 + r, 64);
        float irL = __shfl(invlL, quad * 4 + r, 64);
        int rgH = qw0H + quad * 4 + r;
        int rgL = qw0L + quad * 4 + r;
#pragma unroll
        for (int nj = 0; nj < 4; nj++) {
            out[(size_t)(b * S_LEN + rgH) * D_MODEL + h * D_K + nj * 16 + l15] =
                f2bf(accH[nj][r] * irH);
            out[(size_t)(b * S_LEN + rgL) * D_MODEL + h * D_K + nj * 16 + l15] =
                f2bf(accL[nj][r] * irL);
        }
    }
}

// ---------------------------------------------------------------------------
extern "C" void kernel_launch(void* const* d_in, const int* in_sizes, int n_in,
                              void* d_out, int out_size, void* d_ws, size_t ws_size,
                              hipStream_t stream) {
    const float* x    = (const float*)d_in[0];
    const int*   pos  = (const int*)d_in[1];
    const float* Wqkv = (const float*)d_in[2];
    const float* Wout = (const float*)d_in[3];
    float*       out  = (float*)d_out;

    const int M = B_SZ * S_LEN;   // 4096

    u16* qkvb = (u16*)d_ws;                            // 4096 x 3072
    u16* aob  = qkvb + (size_t)M * 3 * D_MODEL;        // 4096 x 1024
    u16* xb   = aob  + (size_t)M * D_MODEL;            // 4096 x 1024
    u16* wqb  = xb   + (size_t)M * D_MODEL;            // 3072 x 1024
    u16* wob  = wqb  + (size_t)3 * D_MODEL * D_MODEL;  // 1024 x 1024
    u16* vtb  = wob  + (size_t)D_MODEL * D_MODEL;      // 4096 x 1024

    const int na4 = M * D_MODEL / 4;
    const int nb4 = 3 * D_MODEL * D_MODEL / 4;
    const int nc4 = D_MODEL * D_MODEL / 4;
    cast3_f32_bf16<<<(na4 + nb4 + nc4 + 255) / 256, 256, 0, stream>>>(
        x, xb, na4, Wqkv, wqb, nb4, Wout, wob, nc4);

    gemm_bt_mfma<true><<<dim3(3 * D_MODEL / 128, M / 128), 256, 0, stream>>>(
        xb, wqb, qkvb, M, 3 * D_MODEL, D_MODEL);

    rope_bf16<<<(B_SZ * S_LEN * 2 * N_HEADS * 32) / 256, 256, 0, stream>>>(qkvb, pos);

    vtrans<<<dim3(S_LEN / 64, N_HEADS, B_SZ), 256, 0, stream>>>(qkvb, vtb);

    attn_mfma<<<(S_LEN / 64) * N_HEADS * B_SZ / 2, 256, 0, stream>>>(qkvb, vtb, aob);

    gemm_bt_mfma<false><<<dim3(D_MODEL / 128, M / 128), 256, 0, stream>>>(
        aob, wob, out, M, D_MODEL, D_MODEL);
}

// Round 3
// 221.293 us; speedup vs baseline: 1.0369x; 1.0048x over previous
//
#include <hip/hip_runtime.h>
#include <hip/hip_bf16.h>
#include <math.h>

#define D_MODEL 1024
#define N_HEADS 16
#define D_K     64
#define S_LEN   2048
#define B_SZ    2

typedef unsigned short u16;
typedef unsigned int   u32;
using short8 = __attribute__((ext_vector_type(8))) short;
using f32x4  = __attribute__((ext_vector_type(4))) float;

__device__ inline float bf2f(u16 u) { return __uint_as_float((u32)u << 16); }
__device__ inline u16 f2bf(float f) {
    __hip_bfloat16 h = __float2bfloat16(f);   // RNE
    return *(u16*)&h;
}
__device__ inline void gload_lds16(const void* g, void* l) {
    __builtin_amdgcn_global_load_lds(
        (const __attribute__((address_space(1))) unsigned int*)g,
        (__attribute__((address_space(3))) unsigned int*)l, 16, 0, 0);
}

// ---------------------------------------------------------------------------
// fp32 -> bf16 cast for all three inputs in ONE launch (x | W_qkv | W_out).
// ---------------------------------------------------------------------------
__global__ __launch_bounds__(256)
void cast3_f32_bf16(const float* __restrict__ a, u16* __restrict__ ao, int na4,
                    const float* __restrict__ bsrc, u16* __restrict__ bo, int nb4,
                    const float* __restrict__ c, u16* __restrict__ co, int nc4) {
    int j = blockIdx.x * 256 + threadIdx.x;
    const float* src; u16* dst;
    if (j < na4) { src = a; dst = ao; }
    else {
        j -= na4;
        if (j < nb4) { src = bsrc; dst = bo; }
        else {
            j -= nb4;
            if (j >= nc4) return;
            src = c; dst = co;
        }
    }
    float4 v = ((const float4*)src)[j];
    ushort4 u;
    u.x = f2bf(v.x); u.y = f2bf(v.y); u.z = f2bf(v.z); u.w = f2bf(v.w);
    ((ushort4*)dst)[j] = u;
}

// ---------------------------------------------------------------------------
// bf16 MFMA GEMM (m97 structure): C[M][N] = A[M][K] * B[N][K]^T.  (verified)
// ---------------------------------------------------------------------------
template <bool OUT_BF16>
__global__ __launch_bounds__(256)
void gemm_bt_mfma(const u16* __restrict__ A, const u16* __restrict__ B,
                  void* __restrict__ Cout, int M, int N, int K) {
    __shared__ u16 As[128 * 32];
    __shared__ u16 Bs[128 * 32];
    const int tid  = threadIdx.x;
    const int lane = tid & 63;
    const int wv   = tid >> 6;
    const int wm   = wv >> 1, wn = wv & 1;
    const int row0 = blockIdx.y * 128;
    const int col0 = blockIdx.x * 128;

    const int lr = lane >> 2;
    const int lc = (lane & 3) * 8;

    f32x4 acc[4][4] = {};

    for (int k0 = 0; k0 < K; k0 += 32) {
#pragma unroll
        for (int t = 0; t < 2; t++) {
            int rblk = wv * 32 + t * 16;
            gload_lds16(A + (size_t)(row0 + rblk + lr) * K + k0 + lc, &As[rblk * 32]);
            gload_lds16(B + (size_t)(col0 + rblk + lr) * K + k0 + lc, &Bs[rblk * 32]);
        }
        __syncthreads();

        short8 af[4], bfr[4];
#pragma unroll
        for (int mi = 0; mi < 4; mi++)
            af[mi] = *(const short8*)&As[(wm * 64 + mi * 16 + (lane & 15)) * 32 + (lane >> 4) * 8];
#pragma unroll
        for (int nj = 0; nj < 4; nj++)
            bfr[nj] = *(const short8*)&Bs[(wn * 64 + nj * 16 + (lane & 15)) * 32 + (lane >> 4) * 8];
#pragma unroll
        for (int mi = 0; mi < 4; mi++)
#pragma unroll
            for (int nj = 0; nj < 4; nj++)
                acc[mi][nj] = __builtin_amdgcn_mfma_f32_16x16x32_bf16(
                    af[mi], bfr[nj], acc[mi][nj], 0, 0, 0);
        __syncthreads();
    }

    const int cr = (lane >> 4) * 4;
    const int cc = lane & 15;
#pragma unroll
    for (int mi = 0; mi < 4; mi++) {
#pragma unroll
        for (int nj = 0; nj < 4; nj++) {
            int c = col0 + wn * 64 + nj * 16 + cc;
#pragma unroll
            for (int r = 0; r < 4; r++) {
                int rr = row0 + wm * 64 + mi * 16 + cr + r;
                if (OUT_BF16)
                    ((u16*)Cout)[(size_t)rr * N + c] = f2bf(acc[mi][nj][r]);
                else
                    ((float*)Cout)[(size_t)rr * N + c] = acc[mi][nj][r];
            }
        }
    }
}

// ---------------------------------------------------------------------------
// RoPE in place on bf16 qkv (Q and K slices); Q additionally scaled by
// 1/sqrt(d_k).
// ---------------------------------------------------------------------------
__global__ __launch_bounds__(256)
void rope_bf16(u16* __restrict__ qkv, const int* __restrict__ pos) {
    int idx = blockIdx.x * blockDim.x + threadIdx.x;
    int j = idx & 31;
    int h = (idx >> 5) & 15;
    int w = (idx >> 9) & 1;
    int s = (idx >> 10) & 2047;
    int b = idx >> 21;

    float p = (float)pos[s];
    float inv_freq = __powf(10000.0f, -(float)(2 * j) / 64.0f);
    float ang = p * inv_freq;
    float sn, cs;
    sincosf(ang, &sn, &cs);
    float sc = (w == 0) ? 0.125f : 1.0f;

    size_t base = (((size_t)(b * S_LEN + s) * 3 + w) * D_MODEL) + h * D_K + 2 * j;
    float x1 = bf2f(qkv[base]);
    float x2 = bf2f(qkv[base + 1]);
    qkv[base]     = f2bf((x1 * cs - x2 * sn) * sc);
    qkv[base + 1] = f2bf((x1 * sn + x2 * cs) * sc);
}

// ---------------------------------------------------------------------------
// V transpose: qkv V slice (B,S,3,H,D) -> VT (B,H,D,S). 64x64 LDS tile.
// ---------------------------------------------------------------------------
__global__ __launch_bounds__(256)
void vtrans(const u16* __restrict__ qkv, u16* __restrict__ VT) {
    __shared__ u16 t[64][68];
    const int st = blockIdx.x, h = blockIdx.y, b = blockIdx.z;
    const int tid = threadIdx.x;
    const int bh = b * N_HEADS + h;

#pragma unroll
    for (int i = 0; i < 4; i++) {
        int e  = tid + i * 256;
        int sl = e >> 4;
        int c4 = e & 15;
        ushort4 v = *(const ushort4*)&qkv[((size_t)(b * S_LEN + st * 64 + sl) * 3 + 2) * D_MODEL
                                          + h * D_K + c4 * 4];
        *(ushort4*)&t[sl][c4 * 4] = v;
    }
    __syncthreads();
#pragma unroll
    for (int i = 0; i < 4; i++) {
        int e  = tid + i * 256;
        int d  = e >> 4;
        int s4 = e & 15;
        ushort4 o;
        o.x = t[s4 * 4 + 0][d];
        o.y = t[s4 * 4 + 1][d];
        o.z = t[s4 * 4 + 2][d];
        o.w = t[s4 * 4 + 3][d];
        *(ushort4*)&VT[((size_t)bh * D_K + d) * S_LEN + st * 64 + s4 * 4] = o;
    }
}

// ---------------------------------------------------------------------------
// One attention step for one 16-query wave-tile against the 64-key tile
// currently resident in LDS (Ksc/Vsc point at buffer [cur]).
//
// v5: O is accumulated TRANSPOSED (O^T = V^T * P^T): PV operands swapped
// (A=V^T frag, B=P^T frag -- both reads identical to v4's vf/pf).  O^T
// C-layout col = l15 = query, so alpha/invl (owned by lane l15 = query)
// apply as plain per-lane multiplies: the 4 broadcast __shfl per step and
// the 2 epilogue __shfl are GONE from the serial chain.
// Plus T13 defer-max (exact refactoring): skip max-update + O-rescale when
// __all(rmax <= mq+8); P bounded by e^8, f32 accum has headroom.
// ---------------------------------------------------------------------------
__device__ __forceinline__ void attn_step(
    const u16* __restrict__ Ksc, const u16* __restrict__ Vsc,
    u16* __restrict__ Psw,
    short8 (&qf)[2], f32x4 (&acc)[4], float& mq, float& lq,
    int k0, int qw0, bool diag, int l15, int quad)
{
    // ---- S^T = K*Q^T : s[nj] rows=keys nj*16+quad*4+r, col=query l15 ----
    f32x4 s[4] = {};
    __builtin_amdgcn_s_setprio(1);
#pragma unroll
    for (int kf = 0; kf < 2; kf++)
#pragma unroll
        for (int nj = 0; nj < 4; nj++) {
            short8 kfr = *(const short8*)&Ksc[kf * 2048 + (nj * 16 + l15) * 32 + quad * 8];
            s[nj] = __builtin_amdgcn_mfma_f32_16x16x32_bf16(kfr, qf[kf], s[nj], 0, 0, 0);
        }
    __builtin_amdgcn_s_setprio(0);

    // ---- causal mask (diagonal tile only) ----
    if (diag) {
        const int row_g = qw0 + l15;
#pragma unroll
        for (int nj = 0; nj < 4; nj++)
#pragma unroll
            for (int r = 0; r < 4; r++) {
                int key_g = k0 + nj * 16 + quad * 4 + r;
                if (key_g > row_g) s[nj][r] = -INFINITY;
            }
    }

    // ---- online softmax: one query per lane, 16 keys in-lane ----
    float rmax = s[0][0];
#pragma unroll
    for (int nj = 0; nj < 4; nj++)
#pragma unroll
        for (int r = 0; r < 4; r++) rmax = fmaxf(rmax, s[nj][r]);
    rmax = fmaxf(rmax, __shfl_xor(rmax, 16, 64));
    rmax = fmaxf(rmax, __shfl_xor(rmax, 32, 64));

    // T13 defer-max: only touch mq / rescale O when the max actually grew.
    // Exact refactoring (P = exp(s - mq) with stale mq; lq/acc consistent).
    if (!__all(rmax <= mq + 8.f)) {
        float mn = fmaxf(mq, rmax);
        float alpha = __expf(mq - mn);
        mq = mn;
        lq *= alpha;
        // O^T: col = l15 = query -> alpha applies per-lane, NO shfl.
#pragma unroll
        for (int nj = 0; nj < 4; nj++)
#pragma unroll
            for (int r = 0; r < 4; r++) acc[nj][r] *= alpha;
    }

    float rsum = 0.f;
#pragma unroll
    for (int nj = 0; nj < 4; nj++)
#pragma unroll
        for (int r = 0; r < 4; r++) {
            float p = __expf(s[nj][r] - mq);
            s[nj][r] = p;
            rsum += p;
        }
    rsum += __shfl_xor(rsum, 16, 64);
    rsum += __shfl_xor(rsum, 32, 64);
    lq += rsum;

    // ---- P (bf16 pairs) -> wave-private LDS strip [query][key] ----
#pragma unroll
    for (int nj = 0; nj < 4; nj++) {
        u32 lo = ((u32)f2bf(s[nj][1]) << 16) | f2bf(s[nj][0]);
        u32 hi = ((u32)f2bf(s[nj][3]) << 16) | f2bf(s[nj][2]);
        uint2 pk; pk.x = lo; pk.y = hi;
        *(uint2*)&Psw[l15 * 68 + nj * 16 + quad * 4] = pk;
    }
    // same-wave LDS RAW -> compiler inserts lgkmcnt wait

    // ---- O^T += V^T*P^T : A=V^T[m=d][k=key], B=P^T[n=query][k=key] ----
    // acc[nj] rows = d = nj*16 + quad*4 + r, col = query = l15.
    __builtin_amdgcn_s_setprio(1);
#pragma unroll
    for (int kf = 0; kf < 2; kf++) {
        const u16* pp = &Psw[l15 * 68 + kf * 32 + quad * 8];
        uint2 plo = *(const uint2*)pp;
        uint2 phi = *(const uint2*)(pp + 4);
        u32 praw[4] = { plo.x, plo.y, phi.x, phi.y };
        short8 pf = *(const short8*)praw;
#pragma unroll
        for (int nj = 0; nj < 4; nj++) {
            short8 vf = *(const short8*)&Vsc[kf * 2048 + (nj * 16 + l15) * 32 + quad * 8];
            acc[nj] = __builtin_amdgcn_mfma_f32_16x16x32_bf16(vf, pf, acc[nj], 0, 0, 0);
        }
    }
    __builtin_amdgcn_s_setprio(0);
}

// ---------------------------------------------------------------------------
// MFMA flash attention v5 (causal), S^T formulation, PAIRED q-tiles, O^T acc.
//
// vs v4 (60.2 us, MfmaUtil 11.6%, VALUBusy 41%, Occ 17%): latency-chain-
// bound at the structural 8-waves/CU cap -> shorten the per-step serial
// chain instead of chasing TLP: O^T orientation (-4 broadcast shfl/step,
// -2 epilogue shfl) + T13 defer-max (skips alpha-exp + 16-mul rescale on
// almost every tile).  Pairing, XCD pinning, 2-phase dbuf, setprio kept.
// ---------------------------------------------------------------------------
__global__ __launch_bounds__(256)
void attn_mfma(const u16* __restrict__ qkv, const u16* __restrict__ VT,
               u16* __restrict__ out) {
    __shared__ u16 Ks[2][2][64 * 32];    // [buf][kf d-chunk][key*32 + dL]
    __shared__ u16 VsT[2][2][64 * 32];   // [buf][kc key-chunk][d*32 + kL]
    __shared__ u16 Ps[2][4][16 * 68];    // [tile][wave][query 16][key 64 + pad]

    const int tid  = threadIdx.x;
    const int lane = tid & 63;
    const int wv   = tid >> 6;

    // XCD-pinned paired decode (bijective over bid 0..511):
    //   xcd = bid&7; idx = bid>>3; bh = xcd*4 + (idx>>4); pr = idx&15;
    //   q-tiles qtH = 31-pr (long) and qtL = pr (short).
    const int bid = blockIdx.x;
    const int idx = bid >> 3;
    const int bh  = (bid & 7) * 4 + (idx >> 4);
    const int pr  = idx & 15;
    const int qtH = 31 - pr;
    const int qtL = pr;
    const int h   = bh & (N_HEADS - 1);
    const int b   = bh >> 4;

    const int l15  = lane & 15;
    const int quad = lane >> 4;
    const int qw0H = qtH * 64 + wv * 16;
    const int qw0L = qtL * 64 + wv * 16;

    const size_t vtb = (size_t)bh * D_K * S_LEN;
    u16* PswH = &Ps[0][wv][0];
    u16* PswL = &Ps[1][wv][0];

    const int lr = lane >> 2;
    const int lc = (lane & 3) * 8;

    // Q fragments (B-operand layout [n=query l15][k=d quad*8+j]); Q pre-scaled.
    short8 qfH[2], qfL[2];
#pragma unroll
    for (int kf = 0; kf < 2; kf++) {
        qfH[kf] = *(const short8*)&qkv[((size_t)(b * S_LEN + qw0H + l15) * 3 + 0) * D_MODEL
                                       + h * D_K + kf * 32 + quad * 8];
        qfL[kf] = *(const short8*)&qkv[((size_t)(b * S_LEN + qw0L + l15) * 3 + 0) * D_MODEL
                                       + h * D_K + kf * 32 + quad * 8];
    }

    f32x4 accH[4] = {}, accL[4] = {};
    float mqH = -INFINITY, lqH = 0.f;
    float mqL = -INFINITY, lqL = 0.f;

    // async-stage K/V tile kts into LDS buffer bf (wave-uniform LDS base,
    // lane-linear dest -- the gload_lds contract).
    auto STAGE = [&](int kts, int bf) {
        const int k0s = kts * 64;
#pragma unroll
        for (int kf = 0; kf < 2; kf++)
            gload_lds16(qkv + ((size_t)(b * S_LEN + k0s + wv * 16 + lr) * 3 + 1) * D_MODEL
                            + h * D_K + kf * 32 + lc,
                        &Ks[bf][kf][(wv * 16) * 32]);
#pragma unroll
        for (int kc = 0; kc < 2; kc++)
            gload_lds16(VT + vtb + (size_t)(wv * 16 + lr) * S_LEN + k0s + kc * 32 + lc,
                        &VsT[bf][kc][(wv * 16) * 32]);
    };

    STAGE(0, 0);
    __syncthreads();            // vmcnt(0) drain -> tile 0 resident

    int cur = 0;
    for (int kt = 0; kt <= qtH; kt++) {
        const int k0 = kt * 64;

        // prefetch next tile into the other buffer; latency hides under
        // this iteration's compute, retired by the end-of-iter barrier.
        if (kt < qtH) STAGE(kt + 1, cur ^ 1);

        const u16* Ksc = &Ks[cur][0][0];
        const u16* Vsc = &VsT[cur][0][0];

        attn_step(Ksc, Vsc, PswH, qfH, accH, mqH, lqH,
                  k0, qw0H, kt == qtH, l15, quad);
        if (kt <= qtL)
            attn_step(Ksc, Vsc, PswL, qfL, accL, mqL, lqL,
                      k0, qw0L, kt == qtL, l15, quad);

        // retire prefetch (vmcnt 0) + fence buffer swap, one barrier/iter
        __syncthreads();
        cur ^= 1;
    }

    // ---- epilogue: O^T -> out.  lane(l15,quad): query = qw0+l15,
    //      d = nj*16 + quad*4 + r (r contiguous -> ushort4 stores).
    float invlH = 1.f / lqH;
    float invlL = 1.f / lqL;
#pragma unroll
    for (int nj = 0; nj < 4; nj++) {
        ushort4 oH, oL;
        oH.x = f2bf(accH[nj][0] * invlH); oH.y = f2bf(accH[nj][1] * invlH);
        oH.z = f2bf(accH[nj][2] * invlH); oH.w = f2bf(accH[nj][3] * invlH);
        oL.x = f2bf(accL[nj][0] * invlL); oL.y = f2bf(accL[nj][1] * invlL);
        oL.z = f2bf(accL[nj][2] * invlL); oL.w = f2bf(accL[nj][3] * invlL);
        *(ushort4*)&out[(size_t)(b * S_LEN + qw0H + l15) * D_MODEL
                        + h * D_K + nj * 16 + quad * 4] = oH;
        *(ushort4*)&out[(size_t)(b * S_LEN + qw0L + l15) * D_MODEL
                        + h * D_K + nj * 16 + quad * 4] = oL;
    }
}

// ---------------------------------------------------------------------------
extern "C" void kernel_launch(void* const* d_in, const int* in_sizes, int n_in,
                              void* d_out, int out_size, void* d_ws, size_t ws_size,
                              hipStream_t stream) {
    const float* x    = (const float*)d_in[0];
    const int*   pos  = (const int*)d_in[1];
    const float* Wqkv = (const float*)d_in[2];
    const float* Wout = (const float*)d_in[3];
    float*       out  = (float*)d_out;

    const int M = B_SZ * S_LEN;   // 4096

    u16* qkvb = (u16*)d_ws;                            // 4096 x 3072
    u16* aob  = qkvb + (size_t)M * 3 * D_MODEL;        // 4096 x 1024
    u16* xb   = aob  + (size_t)M * D_MODEL;            // 4096 x 1024
    u16* wqb  = xb   + (size_t)M * D_MODEL;            // 3072 x 1024
    u16* wob  = wqb  + (size_t)3 * D_MODEL * D_MODEL;  // 1024 x 1024
    u16* vtb  = wob  + (size_t)D_MODEL * D_MODEL;      // 4096 x 1024

    const int na4 = M * D_MODEL / 4;
    const int nb4 = 3 * D_MODEL * D_MODEL / 4;
    const int nc4 = D_MODEL * D_MODEL / 4;
    cast3_f32_bf16<<<(na4 + nb4 + nc4 + 255) / 256, 256, 0, stream>>>(
        x, xb, na4, Wqkv, wqb, nb4, Wout, wob, nc4);

    gemm_bt_mfma<true><<<dim3(3 * D_MODEL / 128, M / 128), 256, 0, stream>>>(
        xb, wqb, qkvb, M, 3 * D_MODEL, D_MODEL);

    rope_bf16<<<(B_SZ * S_LEN * 2 * N_HEADS * 32) / 256, 256, 0, stream>>>(qkvb, pos);

    vtrans<<<dim3(S_LEN / 64, N_HEADS, B_SZ), 256, 0, stream>>>(qkvb, vtb);

    attn_mfma<<<(S_LEN / 64) * N_HEADS * B_SZ / 2, 256, 0, stream>>>(qkvb, vtb, aob);

    gemm_bt_mfma<false><<<dim3(D_MODEL / 128, M / 128), 256, 0, stream>>>(
        aob, wob, out, M, D_MODEL, D_MODEL);
}

// Round 4
// 216.230 us; speedup vs baseline: 1.0612x; 1.0234x over previous
//
#include <hip/hip_runtime.h>
#include <hip/hip_bf16.h>
#include <math.h>

#define D_MODEL 1024
#define N_HEADS 16
#define D_K     64
#define S_LEN   2048
#define B_SZ    2

typedef unsigned short u16;
typedef unsigned int   u32;
using short8 = __attribute__((ext_vector_type(8))) short;
using f32x4  = __attribute__((ext_vector_type(4))) float;

__device__ inline float bf2f(u16 u) { return __uint_as_float((u32)u << 16); }
__device__ inline u16 f2bf(float f) {
    __hip_bfloat16 h = __float2bfloat16(f);   // RNE
    return *(u16*)&h;
}
__device__ inline void gload_lds16(const void* g, void* l) {
    __builtin_amdgcn_global_load_lds(
        (const __attribute__((address_space(1))) unsigned int*)g,
        (__attribute__((address_space(3))) unsigned int*)l, 16, 0, 0);
}

// ---------------------------------------------------------------------------
// fp32 -> bf16 cast for all three inputs in ONE launch (x | W_qkv | W_out).
// ---------------------------------------------------------------------------
__global__ __launch_bounds__(256)
void cast3_f32_bf16(const float* __restrict__ a, u16* __restrict__ ao, int na4,
                    const float* __restrict__ bsrc, u16* __restrict__ bo, int nb4,
                    const float* __restrict__ c, u16* __restrict__ co, int nc4) {
    int j = blockIdx.x * 256 + threadIdx.x;
    const float* src; u16* dst;
    if (j < na4) { src = a; dst = ao; }
    else {
        j -= na4;
        if (j < nb4) { src = bsrc; dst = bo; }
        else {
            j -= nb4;
            if (j >= nc4) return;
            src = c; dst = co;
        }
    }
    float4 v = ((const float4*)src)[j];
    ushort4 u;
    u.x = f2bf(v.x); u.y = f2bf(v.y); u.z = f2bf(v.z); u.w = f2bf(v.w);
    ((ushort4*)dst)[j] = u;
}

// ---------------------------------------------------------------------------
// bf16 MFMA GEMM (m97 structure): C[M][N] = A[M][K] * B[N][K]^T.  (verified)
// ---------------------------------------------------------------------------
template <bool OUT_BF16>
__global__ __launch_bounds__(256)
void gemm_bt_mfma(const u16* __restrict__ A, const u16* __restrict__ B,
                  void* __restrict__ Cout, int M, int N, int K) {
    __shared__ u16 As[128 * 32];
    __shared__ u16 Bs[128 * 32];
    const int tid  = threadIdx.x;
    const int lane = tid & 63;
    const int wv   = tid >> 6;
    const int wm   = wv >> 1, wn = wv & 1;
    const int row0 = blockIdx.y * 128;
    const int col0 = blockIdx.x * 128;

    const int lr = lane >> 2;
    const int lc = (lane & 3) * 8;

    f32x4 acc[4][4] = {};

    for (int k0 = 0; k0 < K; k0 += 32) {
#pragma unroll
        for (int t = 0; t < 2; t++) {
            int rblk = wv * 32 + t * 16;
            gload_lds16(A + (size_t)(row0 + rblk + lr) * K + k0 + lc, &As[rblk * 32]);
            gload_lds16(B + (size_t)(col0 + rblk + lr) * K + k0 + lc, &Bs[rblk * 32]);
        }
        __syncthreads();

        short8 af[4], bfr[4];
#pragma unroll
        for (int mi = 0; mi < 4; mi++)
            af[mi] = *(const short8*)&As[(wm * 64 + mi * 16 + (lane & 15)) * 32 + (lane >> 4) * 8];
#pragma unroll
        for (int nj = 0; nj < 4; nj++)
            bfr[nj] = *(const short8*)&Bs[(wn * 64 + nj * 16 + (lane & 15)) * 32 + (lane >> 4) * 8];
#pragma unroll
        for (int mi = 0; mi < 4; mi++)
#pragma unroll
            for (int nj = 0; nj < 4; nj++)
                acc[mi][nj] = __builtin_amdgcn_mfma_f32_16x16x32_bf16(
                    af[mi], bfr[nj], acc[mi][nj], 0, 0, 0);
        __syncthreads();
    }

    const int cr = (lane >> 4) * 4;
    const int cc = lane & 15;
#pragma unroll
    for (int mi = 0; mi < 4; mi++) {
#pragma unroll
        for (int nj = 0; nj < 4; nj++) {
            int c = col0 + wn * 64 + nj * 16 + cc;
#pragma unroll
            for (int r = 0; r < 4; r++) {
                int rr = row0 + wm * 64 + mi * 16 + cr + r;
                if (OUT_BF16)
                    ((u16*)Cout)[(size_t)rr * N + c] = f2bf(acc[mi][nj][r]);
                else
                    ((float*)Cout)[(size_t)rr * N + c] = acc[mi][nj][r];
            }
        }
    }
}

// ---------------------------------------------------------------------------
// RoPE in place on bf16 qkv (Q and K slices); Q additionally scaled by
// 1/sqrt(d_k).
// ---------------------------------------------------------------------------
__global__ __launch_bounds__(256)
void rope_bf16(u16* __restrict__ qkv, const int* __restrict__ pos) {
    int idx = blockIdx.x * blockDim.x + threadIdx.x;
    int j = idx & 31;
    int h = (idx >> 5) & 15;
    int w = (idx >> 9) & 1;
    int s = (idx >> 10) & 2047;
    int b = idx >> 21;

    float p = (float)pos[s];
    float inv_freq = __powf(10000.0f, -(float)(2 * j) / 64.0f);
    float ang = p * inv_freq;
    float sn, cs;
    sincosf(ang, &sn, &cs);
    float sc = (w == 0) ? 0.125f : 1.0f;

    size_t base = (((size_t)(b * S_LEN + s) * 3 + w) * D_MODEL) + h * D_K + 2 * j;
    float x1 = bf2f(qkv[base]);
    float x2 = bf2f(qkv[base + 1]);
    qkv[base]     = f2bf((x1 * cs - x2 * sn) * sc);
    qkv[base + 1] = f2bf((x1 * sn + x2 * cs) * sc);
}

// ---------------------------------------------------------------------------
// V transpose: qkv V slice (B,S,3,H,D) -> VT (B,H,D,S). 64x64 LDS tile.
// ---------------------------------------------------------------------------
__global__ __launch_bounds__(256)
void vtrans(const u16* __restrict__ qkv, u16* __restrict__ VT) {
    __shared__ u16 t[64][68];
    const int st = blockIdx.x, h = blockIdx.y, b = blockIdx.z;
    const int tid = threadIdx.x;
    const int bh = b * N_HEADS + h;

#pragma unroll
    for (int i = 0; i < 4; i++) {
        int e  = tid + i * 256;
        int sl = e >> 4;
        int c4 = e & 15;
        ushort4 v = *(const ushort4*)&qkv[((size_t)(b * S_LEN + st * 64 + sl) * 3 + 2) * D_MODEL
                                          + h * D_K + c4 * 4];
        *(ushort4*)&t[sl][c4 * 4] = v;
    }
    __syncthreads();
#pragma unroll
    for (int i = 0; i < 4; i++) {
        int e  = tid + i * 256;
        int d  = e >> 4;
        int s4 = e & 15;
        ushort4 o;
        o.x = t[s4 * 4 + 0][d];
        o.y = t[s4 * 4 + 1][d];
        o.z = t[s4 * 4 + 2][d];
        o.w = t[s4 * 4 + 3][d];
        *(ushort4*)&VT[((size_t)bh * D_K + d) * S_LEN + st * 64 + s4 * 4] = o;
    }
}

// ---------------------------------------------------------------------------
// One attention step for one 16-query wave-tile against the 64-key tile
// resident in LDS.  S^T = K*Q^T; online softmax per lane (one query);
// O^T = V^T*P^T accumulated in registers (v5-verified layout); T13 defer-max.
// ---------------------------------------------------------------------------
__device__ __forceinline__ void attn_step(
    const u16* __restrict__ Ksc, const u16* __restrict__ Vsc,
    u16* __restrict__ Psw,
    short8 (&qf)[2], f32x4 (&acc)[4], float& mq, float& lq,
    int k0, int qw0, bool diag, int l15, int quad)
{
    // ---- S^T = K*Q^T : s[nj] rows=keys nj*16+quad*4+r, col=query l15 ----
    f32x4 s[4] = {};
    __builtin_amdgcn_s_setprio(1);
#pragma unroll
    for (int kf = 0; kf < 2; kf++)
#pragma unroll
        for (int nj = 0; nj < 4; nj++) {
            short8 kfr = *(const short8*)&Ksc[kf * 2048 + (nj * 16 + l15) * 32 + quad * 8];
            s[nj] = __builtin_amdgcn_mfma_f32_16x16x32_bf16(kfr, qf[kf], s[nj], 0, 0, 0);
        }
    __builtin_amdgcn_s_setprio(0);

    // ---- causal mask (diagonal tile only) ----
    if (diag) {
        const int row_g = qw0 + l15;
#pragma unroll
        for (int nj = 0; nj < 4; nj++)
#pragma unroll
            for (int r = 0; r < 4; r++) {
                int key_g = k0 + nj * 16 + quad * 4 + r;
                if (key_g > row_g) s[nj][r] = -INFINITY;
            }
    }

    // ---- online softmax: one query per lane, 16 keys in-lane ----
    float rmax = s[0][0];
#pragma unroll
    for (int nj = 0; nj < 4; nj++)
#pragma unroll
        for (int r = 0; r < 4; r++) rmax = fmaxf(rmax, s[nj][r]);
    rmax = fmaxf(rmax, __shfl_xor(rmax, 16, 64));
    rmax = fmaxf(rmax, __shfl_xor(rmax, 32, 64));

    // T13 defer-max: only touch mq / rescale O when the max actually grew.
    if (!__all(rmax <= mq + 8.f)) {
        float mn = fmaxf(mq, rmax);
        float alpha = __expf(mq - mn);
        mq = mn;
        lq *= alpha;
#pragma unroll
        for (int nj = 0; nj < 4; nj++)
#pragma unroll
            for (int r = 0; r < 4; r++) acc[nj][r] *= alpha;
    }

    float rsum = 0.f;
#pragma unroll
    for (int nj = 0; nj < 4; nj++)
#pragma unroll
        for (int r = 0; r < 4; r++) {
            float p = __expf(s[nj][r] - mq);
            s[nj][r] = p;
            rsum += p;
        }
    rsum += __shfl_xor(rsum, 16, 64);
    rsum += __shfl_xor(rsum, 32, 64);
    lq += rsum;

    // ---- P (bf16 pairs) -> wave-private LDS strip [query][key] ----
#pragma unroll
    for (int nj = 0; nj < 4; nj++) {
        u32 lo = ((u32)f2bf(s[nj][1]) << 16) | f2bf(s[nj][0]);
        u32 hi = ((u32)f2bf(s[nj][3]) << 16) | f2bf(s[nj][2]);
        uint2 pk; pk.x = lo; pk.y = hi;
        *(uint2*)&Psw[l15 * 68 + nj * 16 + quad * 4] = pk;
    }
    // same-wave LDS RAW -> compiler inserts lgkmcnt wait

    // ---- O^T += V^T*P^T : acc[nj] rows = d = nj*16+quad*4+r, col = q = l15 --
    __builtin_amdgcn_s_setprio(1);
#pragma unroll
    for (int kf = 0; kf < 2; kf++) {
        const u16* pp = &Psw[l15 * 68 + kf * 32 + quad * 8];
        uint2 plo = *(const uint2*)pp;
        uint2 phi = *(const uint2*)(pp + 4);
        u32 praw[4] = { plo.x, plo.y, phi.x, phi.y };
        short8 pf = *(const short8*)praw;
#pragma unroll
        for (int nj = 0; nj < 4; nj++) {
            short8 vf = *(const short8*)&Vsc[kf * 2048 + (nj * 16 + l15) * 32 + quad * 8];
            acc[nj] = __builtin_amdgcn_mfma_f32_16x16x32_bf16(vf, pf, acc[nj], 0, 0, 0);
        }
    }
    __builtin_amdgcn_s_setprio(0);
}

// ---------------------------------------------------------------------------
// MFMA flash attention v6 (causal): KEY-SPLIT paired tiles.
//
// vs v5 (57.4 us, Occ 17%): only 2048 waves existed = 2 waves/SIMD total ->
// every DS/exp latency exposed.  Queries are exhausted, so split KEYS:
// pair {pr, 31-pr} is now TWO blocks:
//   role 0: H-tile (qtH=31-pr), kt 0..16            (17 steps)
//   role 1: H-tile, kt 17..qtH  + ALL of L-tile     (15-pr + pr+1 = 16 steps)
// -> 1024 blocks x 4 waves = 4096 waves = 16/CU = 4 waves/SIMD (2x TLP).
// H softmax state merged by attn_combine (exact: m*=max, f=exp(m-m*)).
// L is complete inside role 1 -> written directly.
// Single-buffered K/V (LDS 25 KB) so all 4 blocks/CU are resident; latency
// hiding now comes from cross-block wave overlap instead of the 2-deep
// prefetch.  XCD pinning kept (4 bh per XCD, ~2 MiB KV per L2).
// pr=15 edge: role 1's H range is empty -> writes (-inf,0,0) partial,
// which combine absorbs via exp(-inf)=0.
// ---------------------------------------------------------------------------
__global__ __launch_bounds__(256)
void attn_mfma(const u16* __restrict__ qkv, const u16* __restrict__ VT,
               u16* __restrict__ out, float* __restrict__ partO,
               float* __restrict__ partML) {
    __shared__ u16 Ks[2][64 * 32];    // [kf d-chunk][key*32 + dL]
    __shared__ u16 VsT[2][64 * 32];   // [kc key-chunk][d*32 + kL]
    __shared__ u16 Ps[4][16 * 68];    // per-wave strip, reused by H then L

    const int tid  = threadIdx.x;
    const int lane = tid & 63;
    const int wv   = tid >> 6;

    // XCD-pinned decode (bijective over bid 0..1023):
    //   xcd=bid&7; idx=bid>>3; bh=xcd*4+(idx>>5); rem=idx&31; pr=rem>>1;
    //   role=rem&1.
    const int bid  = blockIdx.x;
    const int idx  = bid >> 3;
    const int bh   = (bid & 7) * 4 + (idx >> 5);
    const int rem  = idx & 31;
    const int pr   = rem >> 1;
    const int role = rem & 1;
    const int qtH  = 31 - pr;
    const int qtL  = pr;
    const int h    = bh & (N_HEADS - 1);
    const int b    = bh >> 4;

    const int l15  = lane & 15;
    const int quad = lane >> 4;
    const int qw0H = qtH * 64 + wv * 16;

    const size_t vtb = (size_t)bh * D_K * S_LEN;
    u16* Psw = &Ps[wv][0];
    const int lr = lane >> 2;
    const int lc = (lane & 3) * 8;

    auto STAGE = [&](int kts) {
        const int k0s = kts * 64;
#pragma unroll
        for (int kf = 0; kf < 2; kf++)
            gload_lds16(qkv + ((size_t)(b * S_LEN + k0s + wv * 16 + lr) * 3 + 1) * D_MODEL
                            + h * D_K + kf * 32 + lc,
                        &Ks[kf][(wv * 16) * 32]);
#pragma unroll
        for (int kc = 0; kc < 2; kc++)
            gload_lds16(VT + vtb + (size_t)(wv * 16 + lr) * S_LEN + k0s + kc * 32 + lc,
                        &VsT[kc][(wv * 16) * 32]);
    };

    // ---- H q-tile: role 0 -> kt in [0,17); role 1 -> kt in [17, qtH] ----
    short8 qfH[2];
#pragma unroll
    for (int kf = 0; kf < 2; kf++)
        qfH[kf] = *(const short8*)&qkv[((size_t)(b * S_LEN + qw0H + l15) * 3 + 0) * D_MODEL
                                       + h * D_K + kf * 32 + quad * 8];
    f32x4 accH[4] = {};
    float mqH = -INFINITY, lqH = 0.f;

    const int kbeg = role ? 17 : 0;
    const int kend = role ? qtH : 16;       // inclusive; role1 empty if qtH<17
    for (int kt = kbeg; kt <= kend; kt++) {
        STAGE(kt);
        __syncthreads();                    // drain -> tile resident
        attn_step(&Ks[0][0], &VsT[0][0], Psw, qfH, accH, mqH, lqH,
                  kt * 64, qw0H, kt == qtH, l15, quad);
        __syncthreads();                    // protect buffer reuse
    }

    // ---- write H partial (unnormalized, defer-max state) ----
    {
        const size_t unit = (size_t)(bh * 16 + (qtH - 16)) * 2 + role;
        float* Od = partO + unit * 4096 + (size_t)(wv * 16 + l15) * 64;
#pragma unroll
        for (int nj = 0; nj < 4; nj++)
            *(f32x4*)&Od[nj * 16 + quad * 4] = accH[nj];
        if (quad == 0) {
            float* ML = partML + unit * 128;
            ML[wv * 16 + l15]      = mqH;
            ML[64 + wv * 16 + l15] = lqH;
        }
    }

    if (!role) return;

    // ---- L q-tile (role 1 only): kt 0..qtL, direct output ----
    const int qw0L = qtL * 64 + wv * 16;
    short8 qfL[2];
#pragma unroll
    for (int kf = 0; kf < 2; kf++)
        qfL[kf] = *(const short8*)&qkv[((size_t)(b * S_LEN + qw0L + l15) * 3 + 0) * D_MODEL
                                       + h * D_K + kf * 32 + quad * 8];
    f32x4 accL[4] = {};
    float mqL = -INFINITY, lqL = 0.f;

    for (int kt = 0; kt <= qtL; kt++) {
        STAGE(kt);
        __syncthreads();
        attn_step(&Ks[0][0], &VsT[0][0], Psw, qfL, accL, mqL, lqL,
                  kt * 64, qw0L, kt == qtL, l15, quad);
        __syncthreads();
    }

    float invl = 1.f / lqL;
#pragma unroll
    for (int nj = 0; nj < 4; nj++) {
        ushort4 o;
        o.x = f2bf(accL[nj][0] * invl); o.y = f2bf(accL[nj][1] * invl);
        o.z = f2bf(accL[nj][2] * invl); o.w = f2bf(accL[nj][3] * invl);
        *(ushort4*)&out[(size_t)(b * S_LEN + qw0L + l15) * D_MODEL
                        + h * D_K + nj * 16 + quad * 4] = o;
    }
}

// ---------------------------------------------------------------------------
// Merge the two key-range partials of each H q-tile and write bf16 output.
// Exact online-softmax merge: m*=max(m0,m1); f_i=exp(m_i-m*);
// out = (f0*O0 + f1*O1) / (f0*l0 + f1*l1).
// ---------------------------------------------------------------------------
__global__ __launch_bounds__(256)
void attn_combine(const float* __restrict__ partO, const float* __restrict__ partML,
                  u16* __restrict__ out) {
    const int t16 = blockIdx.x & 15;
    const int bh  = blockIdx.x >> 4;
    const int h = bh & (N_HEADS - 1), b = bh >> 4;
    const int q0 = (t16 + 16) * 64;
    const int tid = threadIdx.x;
    const int q  = tid >> 2;          // 0..63
    const int d0 = (tid & 3) * 16;    // 0,16,32,48

    const size_t u0 = (size_t)(bh * 16 + t16) * 2;
    const float* O0 = partO + u0 * 4096;
    const float* O1 = O0 + 4096;
    const float* ML0 = partML + u0 * 128;
    const float* ML1 = ML0 + 128;

    float m0 = ML0[q], l0 = ML0[64 + q];
    float m1 = ML1[q], l1 = ML1[64 + q];
    float ms = fmaxf(m0, m1);
    float f0 = __expf(m0 - ms), f1 = __expf(m1 - ms);
    float inv = 1.f / (l0 * f0 + l1 * f1);
    f0 *= inv; f1 *= inv;
#pragma unroll
    for (int i = 0; i < 4; i++) {
        float4 a = *(const float4*)&O0[q * 64 + d0 + i * 4];
        float4 c = *(const float4*)&O1[q * 64 + d0 + i * 4];
        ushort4 o;
        o.x = f2bf(a.x * f0 + c.x * f1);
        o.y = f2bf(a.y * f0 + c.y * f1);
        o.z = f2bf(a.z * f0 + c.z * f1);
        o.w = f2bf(a.w * f0 + c.w * f1);
        *(ushort4*)&out[(size_t)(b * S_LEN + q0 + q) * D_MODEL + h * D_K + d0 + i * 4] = o;
    }
}

// ---------------------------------------------------------------------------
extern "C" void kernel_launch(void* const* d_in, const int* in_sizes, int n_in,
                              void* d_out, int out_size, void* d_ws, size_t ws_size,
                              hipStream_t stream) {
    const float* x    = (const float*)d_in[0];
    const int*   pos  = (const int*)d_in[1];
    const float* Wqkv = (const float*)d_in[2];
    const float* Wout = (const float*)d_in[3];
    float*       out  = (float*)d_out;

    const int M = B_SZ * S_LEN;   // 4096

    u16* qkvb = (u16*)d_ws;                            // 4096 x 3072
    u16* aob  = qkvb + (size_t)M * 3 * D_MODEL;        // 4096 x 1024
    u16* xb   = aob  + (size_t)M * D_MODEL;            // 4096 x 1024
    u16* wqb  = xb   + (size_t)M * D_MODEL;            // 3072 x 1024
    u16* wob  = wqb  + (size_t)3 * D_MODEL * D_MODEL;  // 1024 x 1024
    u16* vtb  = wob  + (size_t)D_MODEL * D_MODEL;      // 4096 x 1024
    float* partO  = (float*)(vtb + (size_t)M * D_MODEL);   // 1024 x 4096 f32
    float* partML = partO + (size_t)1024 * 4096;            // 1024 x 128 f32

    const int na4 = M * D_MODEL / 4;
    const int nb4 = 3 * D_MODEL * D_MODEL / 4;
    const int nc4 = D_MODEL * D_MODEL / 4;
    cast3_f32_bf16<<<(na4 + nb4 + nc4 + 255) / 256, 256, 0, stream>>>(
        x, xb, na4, Wqkv, wqb, nb4, Wout, wob, nc4);

    gemm_bt_mfma<true><<<dim3(3 * D_MODEL / 128, M / 128), 256, 0, stream>>>(
        xb, wqb, qkvb, M, 3 * D_MODEL, D_MODEL);

    rope_bf16<<<(B_SZ * S_LEN * 2 * N_HEADS * 32) / 256, 256, 0, stream>>>(qkvb, pos);

    vtrans<<<dim3(S_LEN / 64, N_HEADS, B_SZ), 256, 0, stream>>>(qkvb, vtb);

    attn_mfma<<<1024, 256, 0, stream>>>(qkvb, vtb, aob, partO, partML);
    attn_combine<<<512, 256, 0, stream>>>(partO, partML, aob);

    gemm_bt_mfma<false><<<dim3(D_MODEL / 128, M / 128), 256, 0, stream>>>(
        aob, wob, out, M, D_MODEL, D_MODEL);
}

// Round 5
// 197.577 us; speedup vs baseline: 1.1614x; 1.0944x over previous
//
#include <hip/hip_runtime.h>
#include <hip/hip_bf16.h>
#include <math.h>

#define D_MODEL 1024
#define N_HEADS 16
#define D_K     64
#define S_LEN   2048
#define B_SZ    2

typedef unsigned short u16;
typedef unsigned int   u32;
using short8  = __attribute__((ext_vector_type(8))) short;
using ushort8 = __attribute__((ext_vector_type(8))) unsigned short;
using f32x4   = __attribute__((ext_vector_type(4))) float;

__device__ inline float bf2f(u16 u) { return __uint_as_float((u32)u << 16); }
__device__ inline u16 f2bf(float f) {
    __hip_bfloat16 h = __float2bfloat16(f);   // RNE
    return *(u16*)&h;
}
__device__ inline void gload_lds16(const void* g, void* l) {
    __builtin_amdgcn_global_load_lds(
        (const __attribute__((address_space(1))) unsigned int*)g,
        (__attribute__((address_space(3))) unsigned int*)l, 16, 0, 0);
}

// ---------------------------------------------------------------------------
// fp32 -> bf16 cast for all three inputs in ONE launch (x | W_qkv | W_out).
// ---------------------------------------------------------------------------
__global__ __launch_bounds__(256)
void cast3_f32_bf16(const float* __restrict__ a, u16* __restrict__ ao, int na4,
                    const float* __restrict__ bsrc, u16* __restrict__ bo, int nb4,
                    const float* __restrict__ c, u16* __restrict__ co, int nc4) {
    int j = blockIdx.x * 256 + threadIdx.x;
    const float* src; u16* dst;
    if (j < na4) { src = a; dst = ao; }
    else {
        j -= na4;
        if (j < nb4) { src = bsrc; dst = bo; }
        else {
            j -= nb4;
            if (j >= nc4) return;
            src = c; dst = co;
        }
    }
    float4 v = ((const float4*)src)[j];
    ushort4 u;
    u.x = f2bf(v.x); u.y = f2bf(v.y); u.z = f2bf(v.z); u.w = f2bf(v.w);
    ((ushort4*)dst)[j] = u;
}

// ---------------------------------------------------------------------------
// bf16 MFMA GEMM (m97 structure): C[M][N] = A[M][K] * B[N][K]^T.  (verified)
// ---------------------------------------------------------------------------
template <bool OUT_BF16>
__global__ __launch_bounds__(256)
void gemm_bt_mfma(const u16* __restrict__ A, const u16* __restrict__ B,
                  void* __restrict__ Cout, int M, int N, int K) {
    __shared__ u16 As[128 * 32];
    __shared__ u16 Bs[128 * 32];
    const int tid  = threadIdx.x;
    const int lane = tid & 63;
    const int wv   = tid >> 6;
    const int wm   = wv >> 1, wn = wv & 1;
    const int row0 = blockIdx.y * 128;
    const int col0 = blockIdx.x * 128;

    const int lr = lane >> 2;
    const int lc = (lane & 3) * 8;

    f32x4 acc[4][4] = {};

    for (int k0 = 0; k0 < K; k0 += 32) {
#pragma unroll
        for (int t = 0; t < 2; t++) {
            int rblk = wv * 32 + t * 16;
            gload_lds16(A + (size_t)(row0 + rblk + lr) * K + k0 + lc, &As[rblk * 32]);
            gload_lds16(B + (size_t)(col0 + rblk + lr) * K + k0 + lc, &Bs[rblk * 32]);
        }
        __syncthreads();

        short8 af[4], bfr[4];
#pragma unroll
        for (int mi = 0; mi < 4; mi++)
            af[mi] = *(const short8*)&As[(wm * 64 + mi * 16 + (lane & 15)) * 32 + (lane >> 4) * 8];
#pragma unroll
        for (int nj = 0; nj < 4; nj++)
            bfr[nj] = *(const short8*)&Bs[(wn * 64 + nj * 16 + (lane & 15)) * 32 + (lane >> 4) * 8];
#pragma unroll
        for (int mi = 0; mi < 4; mi++)
#pragma unroll
            for (int nj = 0; nj < 4; nj++)
                acc[mi][nj] = __builtin_amdgcn_mfma_f32_16x16x32_bf16(
                    af[mi], bfr[nj], acc[mi][nj], 0, 0, 0);
        __syncthreads();
    }

    const int cr = (lane >> 4) * 4;
    const int cc = lane & 15;
#pragma unroll
    for (int mi = 0; mi < 4; mi++) {
#pragma unroll
        for (int nj = 0; nj < 4; nj++) {
            int c = col0 + wn * 64 + nj * 16 + cc;
#pragma unroll
            for (int r = 0; r < 4; r++) {
                int rr = row0 + wm * 64 + mi * 16 + cr + r;
                if (OUT_BF16)
                    ((u16*)Cout)[(size_t)rr * N + c] = f2bf(acc[mi][nj][r]);
                else
                    ((float*)Cout)[(size_t)rr * N + c] = acc[mi][nj][r];
            }
        }
    }
}

// ---------------------------------------------------------------------------
// prep: fused V-transpose + RoPE in one launch (independent slices of qkv).
//   blocks [0, 1024):  V transpose  qkv V slice (B,S,3,H,D) -> VT (B,H,D,S)
//   blocks [1024, 5120): RoPE in place on Q/K slices, Q scaled by 1/8.
// RoPE is vectorized 8 u16 (4 pairs) per thread with exp2f + __sincosf
// (library sincosf/__powf per element was the m205 VALU-bound anti-pattern).
// ---------------------------------------------------------------------------
__global__ __launch_bounds__(256)
void prep_vtrans_rope(u16* __restrict__ qkv, u16* __restrict__ VT,
                      const int* __restrict__ pos) {
    const int bid = blockIdx.x;
    const int tid = threadIdx.x;

    if (bid < 1024) {
        // ---- V transpose: 64x64 LDS tile ----
        __shared__ u16 t[64][68];
        const int st = bid & 31, h = (bid >> 5) & 15, b = bid >> 9;
        const int bh = b * N_HEADS + h;
#pragma unroll
        for (int i = 0; i < 4; i++) {
            int e  = tid + i * 256;
            int sl = e >> 4;
            int c4 = e & 15;
            ushort4 v = *(const ushort4*)&qkv[((size_t)(b * S_LEN + st * 64 + sl) * 3 + 2) * D_MODEL
                                              + h * D_K + c4 * 4];
            *(ushort4*)&t[sl][c4 * 4] = v;
        }
        __syncthreads();
#pragma unroll
        for (int i = 0; i < 4; i++) {
            int e  = tid + i * 256;
            int d  = e >> 4;
            int s4 = e & 15;
            ushort4 o;
            o.x = t[s4 * 4 + 0][d];
            o.y = t[s4 * 4 + 1][d];
            o.z = t[s4 * 4 + 2][d];
            o.w = t[s4 * 4 + 3][d];
            *(ushort4*)&VT[((size_t)bh * D_K + d) * S_LEN + st * 64 + s4 * 4] = o;
        }
        return;
    }

    // ---- RoPE: thread handles 8 consecutive u16 = 4 rotation pairs ----
    int e  = (bid - 1024) * 256 + tid;      // 0 .. 1048575
    int j8 = e & 7;                          // 8-u16 chunk within head dim
    int h  = (e >> 3) & 15;
    int w  = (e >> 7) & 1;                   // 0=Q, 1=K
    int s  = (e >> 8) & 2047;
    int b  = e >> 19;

    float p  = (float)pos[s];
    float sc = (w == 0) ? 0.125f : 1.0f;

    size_t base = (((size_t)(b * S_LEN + s) * 3 + w) * D_MODEL) + h * D_K + j8 * 8;
    ushort8 v = *(const ushort8*)&qkv[base];

    // inv_freq = 10000^(-j/32) = exp2(-j * log2(10000)/32)
    const float C = -0.41524101186092056f;   // -log2(10000)/32
#pragma unroll
    for (int jj = 0; jj < 4; jj++) {
        int j = j8 * 4 + jj;
        float ang = p * exp2f((float)j * C);
        float sn, cs;
        __sincosf(ang, &sn, &cs);
        float x1 = bf2f(v[2 * jj]);
        float x2 = bf2f(v[2 * jj + 1]);
        v[2 * jj]     = f2bf((x1 * cs - x2 * sn) * sc);
        v[2 * jj + 1] = f2bf((x1 * sn + x2 * cs) * sc);
    }
    *(ushort8*)&qkv[base] = v;
}

// ---------------------------------------------------------------------------
// One attention step for one 16-query wave-tile against the 64-key tile
// resident in LDS.  S^T = K*Q^T; online softmax per lane (one query);
// O^T = V^T*P^T accumulated in registers (v5-verified layout); T13 defer-max.
// qsw = quad ^ ((l15>>1)&3): XOR-swizzled K/V chunk index (T2; LDS holds
// swizzled tiles -- see STAGE).  P strip is unswizzled (uses quad).
// ---------------------------------------------------------------------------
__device__ __forceinline__ void attn_step(
    const u16* __restrict__ Ksc, const u16* __restrict__ Vsc,
    u16* __restrict__ Psw,
    short8 (&qf)[2], f32x4 (&acc)[4], float& mq, float& lq,
    int k0, int qw0, bool diag, int l15, int quad, int qsw)
{
    // ---- S^T = K*Q^T : s[nj] rows=keys nj*16+quad*4+r, col=query l15 ----
    f32x4 s[4] = {};
    __builtin_amdgcn_s_setprio(1);
#pragma unroll
    for (int kf = 0; kf < 2; kf++)
#pragma unroll
        for (int nj = 0; nj < 4; nj++) {
            short8 kfr = *(const short8*)&Ksc[kf * 2048 + (nj * 16 + l15) * 32 + qsw * 8];
            s[nj] = __builtin_amdgcn_mfma_f32_16x16x32_bf16(kfr, qf[kf], s[nj], 0, 0, 0);
        }
    __builtin_amdgcn_s_setprio(0);

    // ---- causal mask (diagonal tile only) ----
    if (diag) {
        const int row_g = qw0 + l15;
#pragma unroll
        for (int nj = 0; nj < 4; nj++)
#pragma unroll
            for (int r = 0; r < 4; r++) {
                int key_g = k0 + nj * 16 + quad * 4 + r;
                if (key_g > row_g) s[nj][r] = -INFINITY;
            }
    }

    // ---- online softmax: one query per lane, 16 keys in-lane ----
    float rmax = s[0][0];
#pragma unroll
    for (int nj = 0; nj < 4; nj++)
#pragma unroll
        for (int r = 0; r < 4; r++) rmax = fmaxf(rmax, s[nj][r]);
    rmax = fmaxf(rmax, __shfl_xor(rmax, 16, 64));
    rmax = fmaxf(rmax, __shfl_xor(rmax, 32, 64));

    // T13 defer-max: only touch mq / rescale O when the max actually grew.
    if (!__all(rmax <= mq + 8.f)) {
        float mn = fmaxf(mq, rmax);
        float alpha = __expf(mq - mn);
        mq = mn;
        lq *= alpha;
#pragma unroll
        for (int nj = 0; nj < 4; nj++)
#pragma unroll
            for (int r = 0; r < 4; r++) acc[nj][r] *= alpha;
    }

    float rsum = 0.f;
#pragma unroll
    for (int nj = 0; nj < 4; nj++)
#pragma unroll
        for (int r = 0; r < 4; r++) {
            float p = __expf(s[nj][r] - mq);
            s[nj][r] = p;
            rsum += p;
        }
    rsum += __shfl_xor(rsum, 16, 64);
    rsum += __shfl_xor(rsum, 32, 64);
    lq += rsum;

    // ---- P (bf16 pairs) -> wave-private LDS strip [query][key] ----
#pragma unroll
    for (int nj = 0; nj < 4; nj++) {
        u32 lo = ((u32)f2bf(s[nj][1]) << 16) | f2bf(s[nj][0]);
        u32 hi = ((u32)f2bf(s[nj][3]) << 16) | f2bf(s[nj][2]);
        uint2 pk; pk.x = lo; pk.y = hi;
        *(uint2*)&Psw[l15 * 68 + nj * 16 + quad * 4] = pk;
    }
    // same-wave LDS RAW -> compiler inserts lgkmcnt wait

    // ---- O^T += V^T*P^T : acc[nj] rows = d = nj*16+quad*4+r, col = q = l15 --
    __builtin_amdgcn_s_setprio(1);
#pragma unroll
    for (int kf = 0; kf < 2; kf++) {
        const u16* pp = &Psw[l15 * 68 + kf * 32 + quad * 8];
        uint2 plo = *(const uint2*)pp;
        uint2 phi = *(const uint2*)(pp + 4);
        u32 praw[4] = { plo.x, plo.y, phi.x, phi.y };
        short8 pf = *(const short8*)praw;
#pragma unroll
        for (int nj = 0; nj < 4; nj++) {
            short8 vf = *(const short8*)&Vsc[kf * 2048 + (nj * 16 + l15) * 32 + qsw * 8];
            acc[nj] = __builtin_amdgcn_mfma_f32_16x16x32_bf16(vf, pf, acc[nj], 0, 0, 0);
        }
    }
    __builtin_amdgcn_s_setprio(0);
}

// ---------------------------------------------------------------------------
// MFMA flash attention v7 (causal): KEY-SPLIT paired tiles + T2 LDS swizzle.
//
// vs v6 (49.4 us, Occ 30%, VALUBusy 44%, BANK_CONFLICT 4.33M): the K/V
// fragment reads (row stride 64B, chunk 16B) were an 8-way bank conflict
// (~5 extra cy per LDS op).  Fix per rule #21 (global_load_lds writes
// linearly): pre-swizzle the GLOBAL source chunk (chunk_g = chunk ^
// ((row>>1)&3), m173 pattern) and XOR the read chunk the same way ->
// 2-way (free, m136).  Key-split structure, XCD pinning, defer-max,
// O^T accumulation all unchanged (verified R4).
// ---------------------------------------------------------------------------
__global__ __launch_bounds__(256)
void attn_mfma(const u16* __restrict__ qkv, const u16* __restrict__ VT,
               u16* __restrict__ out, float* __restrict__ partO,
               float* __restrict__ partML) {
    __shared__ u16 Ks[2][64 * 32];    // [kf d-chunk][key*32 + dL]  (swizzled)
    __shared__ u16 VsT[2][64 * 32];   // [kc key-chunk][d*32 + kL]  (swizzled)
    __shared__ u16 Ps[4][16 * 68];    // per-wave strip, reused by H then L

    const int tid  = threadIdx.x;
    const int lane = tid & 63;
    const int wv   = tid >> 6;

    // XCD-pinned decode (bijective over bid 0..1023):
    //   xcd=bid&7; idx=bid>>3; bh=xcd*4+(idx>>5); rem=idx&31; pr=rem>>1;
    //   role=rem&1.
    const int bid  = blockIdx.x;
    const int idx  = bid >> 3;
    const int bh   = (bid & 7) * 4 + (idx >> 5);
    const int rem  = idx & 31;
    const int pr   = rem >> 1;
    const int role = rem & 1;
    const int qtH  = 31 - pr;
    const int qtL  = pr;
    const int h    = bh & (N_HEADS - 1);
    const int b    = bh >> 4;

    const int l15  = lane & 15;
    const int quad = lane >> 4;
    const int qsw  = quad ^ ((l15 >> 1) & 3);       // swizzled read chunk
    const int qw0H = qtH * 64 + wv * 16;

    const size_t vtb = (size_t)bh * D_K * S_LEN;
    u16* Psw = &Ps[wv][0];
    const int lr  = lane >> 2;
    const int csw = ((lane & 3) ^ ((lane >> 3) & 3)) * 8;  // swizzled src chunk

    auto STAGE = [&](int kts) {
        const int k0s = kts * 64;
#pragma unroll
        for (int kf = 0; kf < 2; kf++)
            gload_lds16(qkv + ((size_t)(b * S_LEN + k0s + wv * 16 + lr) * 3 + 1) * D_MODEL
                            + h * D_K + kf * 32 + csw,
                        &Ks[kf][(wv * 16) * 32]);
#pragma unroll
        for (int kc = 0; kc < 2; kc++)
            gload_lds16(VT + vtb + (size_t)(wv * 16 + lr) * S_LEN + k0s + kc * 32 + csw,
                        &VsT[kc][(wv * 16) * 32]);
    };

    // ---- H q-tile: role 0 -> kt in [0,17); role 1 -> kt in [17, qtH] ----
    short8 qfH[2];
#pragma unroll
    for (int kf = 0; kf < 2; kf++)
        qfH[kf] = *(const short8*)&qkv[((size_t)(b * S_LEN + qw0H + l15) * 3 + 0) * D_MODEL
                                       + h * D_K + kf * 32 + quad * 8];
    f32x4 accH[4] = {};
    float mqH = -INFINITY, lqH = 0.f;

    const int kbeg = role ? 17 : 0;
    const int kend = role ? qtH : 16;       // inclusive; role1 empty if qtH<17
    for (int kt = kbeg; kt <= kend; kt++) {
        STAGE(kt);
        __syncthreads();                    // drain -> tile resident
        attn_step(&Ks[0][0], &VsT[0][0], Psw, qfH, accH, mqH, lqH,
                  kt * 64, qw0H, kt == qtH, l15, quad, qsw);
        __syncthreads();                    // protect buffer reuse
    }

    // ---- write H partial (unnormalized, defer-max state) ----
    {
        const size_t unit = (size_t)(bh * 16 + (qtH - 16)) * 2 + role;
        float* Od = partO + unit * 4096 + (size_t)(wv * 16 + l15) * 64;
#pragma unroll
        for (int nj = 0; nj < 4; nj++)
            *(f32x4*)&Od[nj * 16 + quad * 4] = accH[nj];
        if (quad == 0) {
            float* ML = partML + unit * 128;
            ML[wv * 16 + l15]      = mqH;
            ML[64 + wv * 16 + l15] = lqH;
        }
    }

    if (!role) return;

    // ---- L q-tile (role 1 only): kt 0..qtL, direct output ----
    const int qw0L = qtL * 64 + wv * 16;
    short8 qfL[2];
#pragma unroll
    for (int kf = 0; kf < 2; kf++)
        qfL[kf] = *(const short8*)&qkv[((size_t)(b * S_LEN + qw0L + l15) * 3 + 0) * D_MODEL
                                       + h * D_K + kf * 32 + quad * 8];
    f32x4 accL[4] = {};
    float mqL = -INFINITY, lqL = 0.f;

    for (int kt = 0; kt <= qtL; kt++) {
        STAGE(kt);
        __syncthreads();
        attn_step(&Ks[0][0], &VsT[0][0], Psw, qfL, accL, mqL, lqL,
                  kt * 64, qw0L, kt == qtL, l15, quad, qsw);
        __syncthreads();
    }

    float invl = 1.f / lqL;
#pragma unroll
    for (int nj = 0; nj < 4; nj++) {
        ushort4 o;
        o.x = f2bf(accL[nj][0] * invl); o.y = f2bf(accL[nj][1] * invl);
        o.z = f2bf(accL[nj][2] * invl); o.w = f2bf(accL[nj][3] * invl);
        *(ushort4*)&out[(size_t)(b * S_LEN + qw0L + l15) * D_MODEL
                        + h * D_K + nj * 16 + quad * 4] = o;
    }
}

// ---------------------------------------------------------------------------
// Merge the two key-range partials of each H q-tile and write bf16 output.
// Exact online-softmax merge: m*=max(m0,m1); f_i=exp(m_i-m*);
// out = (f0*O0 + f1*O1) / (f0*l0 + f1*l1).
// ---------------------------------------------------------------------------
__global__ __launch_bounds__(256)
void attn_combine(const float* __restrict__ partO, const float* __restrict__ partML,
                  u16* __restrict__ out) {
    const int t16 = blockIdx.x & 15;
    const int bh  = blockIdx.x >> 4;
    const int h = bh & (N_HEADS - 1), b = bh >> 4;
    const int q0 = (t16 + 16) * 64;
    const int tid = threadIdx.x;
    const int q  = tid >> 2;          // 0..63
    const int d0 = (tid & 3) * 16;    // 0,16,32,48

    const size_t u0 = (size_t)(bh * 16 + t16) * 2;
    const float* O0 = partO + u0 * 4096;
    const float* O1 = O0 + 4096;
    const float* ML0 = partML + u0 * 128;
    const float* ML1 = ML0 + 128;

    float m0 = ML0[q], l0 = ML0[64 + q];
    float m1 = ML1[q], l1 = ML1[64 + q];
    float ms = fmaxf(m0, m1);
    float f0 = __expf(m0 - ms), f1 = __expf(m1 - ms);
    float inv = 1.f / (l0 * f0 + l1 * f1);
    f0 *= inv; f1 *= inv;
#pragma unroll
    for (int i = 0; i < 4; i++) {
        float4 a = *(const float4*)&O0[q * 64 + d0 + i * 4];
        float4 c = *(const float4*)&O1[q * 64 + d0 + i * 4];
        ushort4 o;
        o.x = f2bf(a.x * f0 + c.x * f1);
        o.y = f2bf(a.y * f0 + c.y * f1);
        o.z = f2bf(a.z * f0 + c.z * f1);
        o.w = f2bf(a.w * f0 + c.w * f1);
        *(ushort4*)&out[(size_t)(b * S_LEN + q0 + q) * D_MODEL + h * D_K + d0 + i * 4] = o;
    }
}

// ---------------------------------------------------------------------------
extern "C" void kernel_launch(void* const* d_in, const int* in_sizes, int n_in,
                              void* d_out, int out_size, void* d_ws, size_t ws_size,
                              hipStream_t stream) {
    const float* x    = (const float*)d_in[0];
    const int*   pos  = (const int*)d_in[1];
    const float* Wqkv = (const float*)d_in[2];
    const float* Wout = (const float*)d_in[3];
    float*       out  = (float*)d_out;

    const int M = B_SZ * S_LEN;   // 4096

    u16* qkvb = (u16*)d_ws;                            // 4096 x 3072
    u16* aob  = qkvb + (size_t)M * 3 * D_MODEL;        // 4096 x 1024
    u16* xb   = aob  + (size_t)M * D_MODEL;            // 4096 x 1024
    u16* wqb  = xb   + (size_t)M * D_MODEL;            // 3072 x 1024
    u16* wob  = wqb  + (size_t)3 * D_MODEL * D_MODEL;  // 1024 x 1024
    u16* vtb  = wob  + (size_t)D_MODEL * D_MODEL;      // 4096 x 1024
    float* partO  = (float*)(vtb + (size_t)M * D_MODEL);   // 1024 x 4096 f32
    float* partML = partO + (size_t)1024 * 4096;            // 1024 x 128 f32

    const int na4 = M * D_MODEL / 4;
    const int nb4 = 3 * D_MODEL * D_MODEL / 4;
    const int nc4 = D_MODEL * D_MODEL / 4;
    cast3_f32_bf16<<<(na4 + nb4 + nc4 + 255) / 256, 256, 0, stream>>>(
        x, xb, na4, Wqkv, wqb, nb4, Wout, wob, nc4);

    gemm_bt_mfma<true><<<dim3(3 * D_MODEL / 128, M / 128), 256, 0, stream>>>(
        xb, wqb, qkvb, M, 3 * D_MODEL, D_MODEL);

    // fused V-transpose (blocks 0..1023) + vectorized RoPE (blocks 1024..5119)
    prep_vtrans_rope<<<5120, 256, 0, stream>>>(qkvb, vtb, pos);

    attn_mfma<<<1024, 256, 0, stream>>>(qkvb, vtb, aob, partO, partML);
    attn_combine<<<512, 256, 0, stream>>>(partO, partML, aob);

    gemm_bt_mfma<false><<<dim3(D_MODEL / 128, M / 128), 256, 0, stream>>>(
        aob, wob, out, M, D_MODEL, D_MODEL);
}

// Round 7
// 191.288 us; speedup vs baseline: 1.1996x; 1.0329x over previous
//
#include <hip/hip_runtime.h>
#include <hip/hip_bf16.h>
#include <math.h>

#define D_MODEL 1024
#define N_HEADS 16
#define D_K     64
#define S_LEN   2048
#define B_SZ    2

typedef unsigned short u16;
typedef unsigned int   u32;
using short8  = __attribute__((ext_vector_type(8))) short;
using ushort8 = __attribute__((ext_vector_type(8))) unsigned short;
using f32x4   = __attribute__((ext_vector_type(4))) float;

__device__ inline float bf2f(u16 u) { return __uint_as_float((u32)u << 16); }
__device__ inline u16 f2bf(float f) {
    __hip_bfloat16 h = __float2bfloat16(f);   // RNE
    return *(u16*)&h;
}
// raw v_exp_f32 (2^x).  NOTE: __exp2f does not exist in HIP device code
// (glibc math.h macro collision) -- use the amdgcn builtin directly.
__device__ inline float fast_exp2(float x) { return __builtin_amdgcn_exp2f(x); }
__device__ inline void gload_lds16(const void* g, void* l) {
    __builtin_amdgcn_global_load_lds(
        (const __attribute__((address_space(1))) unsigned int*)g,
        (__attribute__((address_space(3))) unsigned int*)l, 16, 0, 0);
}

// ---------------------------------------------------------------------------
// fp32 -> bf16 cast for all three inputs in ONE launch (x | W_qkv | W_out).
// ---------------------------------------------------------------------------
__global__ __launch_bounds__(256)
void cast3_f32_bf16(const float* __restrict__ a, u16* __restrict__ ao, int na4,
                    const float* __restrict__ bsrc, u16* __restrict__ bo, int nb4,
                    const float* __restrict__ c, u16* __restrict__ co, int nc4) {
    int j = blockIdx.x * 256 + threadIdx.x;
    const float* src; u16* dst;
    if (j < na4) { src = a; dst = ao; }
    else {
        j -= na4;
        if (j < nb4) { src = bsrc; dst = bo; }
        else {
            j -= nb4;
            if (j >= nc4) return;
            src = c; dst = co;
        }
    }
    float4 v = ((const float4*)src)[j];
    ushort4 u;
    u.x = f2bf(v.x); u.y = f2bf(v.y); u.z = f2bf(v.z); u.w = f2bf(v.w);
    ((ushort4*)dst)[j] = u;
}

// ---------------------------------------------------------------------------
// bf16 MFMA GEMM (m97 structure): C[M][N] = A[M][K] * B[N][K]^T.  (verified)
// 128x128 tile, 4 waves 2x2.  Used for gemm1 (N=3072, 768 blocks = 3/CU).
// ---------------------------------------------------------------------------
template <bool OUT_BF16>
__global__ __launch_bounds__(256)
void gemm_bt_mfma(const u16* __restrict__ A, const u16* __restrict__ B,
                  void* __restrict__ Cout, int M, int N, int K) {
    __shared__ u16 As[128 * 32];
    __shared__ u16 Bs[128 * 32];
    const int tid  = threadIdx.x;
    const int lane = tid & 63;
    const int wv   = tid >> 6;
    const int wm   = wv >> 1, wn = wv & 1;
    const int row0 = blockIdx.y * 128;
    const int col0 = blockIdx.x * 128;

    const int lr = lane >> 2;
    const int lc = (lane & 3) * 8;

    f32x4 acc[4][4] = {};

    for (int k0 = 0; k0 < K; k0 += 32) {
#pragma unroll
        for (int t = 0; t < 2; t++) {
            int rblk = wv * 32 + t * 16;
            gload_lds16(A + (size_t)(row0 + rblk + lr) * K + k0 + lc, &As[rblk * 32]);
            gload_lds16(B + (size_t)(col0 + rblk + lr) * K + k0 + lc, &Bs[rblk * 32]);
        }
        __syncthreads();

        short8 af[4], bfr[4];
#pragma unroll
        for (int mi = 0; mi < 4; mi++)
            af[mi] = *(const short8*)&As[(wm * 64 + mi * 16 + (lane & 15)) * 32 + (lane >> 4) * 8];
#pragma unroll
        for (int nj = 0; nj < 4; nj++)
            bfr[nj] = *(const short8*)&Bs[(wn * 64 + nj * 16 + (lane & 15)) * 32 + (lane >> 4) * 8];
#pragma unroll
        for (int mi = 0; mi < 4; mi++)
#pragma unroll
            for (int nj = 0; nj < 4; nj++)
                acc[mi][nj] = __builtin_amdgcn_mfma_f32_16x16x32_bf16(
                    af[mi], bfr[nj], acc[mi][nj], 0, 0, 0);
        __syncthreads();
    }

    const int cr = (lane >> 4) * 4;
    const int cc = lane & 15;
#pragma unroll
    for (int mi = 0; mi < 4; mi++) {
#pragma unroll
        for (int nj = 0; nj < 4; nj++) {
            int c = col0 + wn * 64 + nj * 16 + cc;
#pragma unroll
            for (int r = 0; r < 4; r++) {
                int rr = row0 + wm * 64 + mi * 16 + cr + r;
                if (OUT_BF16)
                    ((u16*)Cout)[(size_t)rr * N + c] = f2bf(acc[mi][nj][r]);
                else
                    ((float*)Cout)[(size_t)rr * N + c] = acc[mi][nj][r];
            }
        }
    }
}

// ---------------------------------------------------------------------------
// 64x128-tile GEMM variant for gemm2 (M=4096, N=1024): 128x128 gave only
// 256 blocks = 1 block/CU = 1 wave/SIMD (zero latency hiding).  64-row
// tiles -> 512 blocks = 2/CU.  Same staging/fragment/C-write pattern,
// waves 2x2 each owning 32x64 (acc 2x4).  f32 output only.
// ---------------------------------------------------------------------------
__global__ __launch_bounds__(256)
void gemm_bt_mfma_64r(const u16* __restrict__ A, const u16* __restrict__ B,
                      float* __restrict__ Cout, int M, int N, int K) {
    __shared__ u16 As[64 * 32];
    __shared__ u16 Bs[128 * 32];
    const int tid  = threadIdx.x;
    const int lane = tid & 63;
    const int wv   = tid >> 6;
    const int wm   = wv >> 1, wn = wv & 1;
    const int row0 = blockIdx.y * 64;
    const int col0 = blockIdx.x * 128;

    const int lr = lane >> 2;
    const int lc = (lane & 3) * 8;

    f32x4 acc[2][4] = {};

    for (int k0 = 0; k0 < K; k0 += 32) {
        gload_lds16(A + (size_t)(row0 + wv * 16 + lr) * K + k0 + lc, &As[(wv * 16) * 32]);
#pragma unroll
        for (int t = 0; t < 2; t++) {
            int rblk = wv * 32 + t * 16;
            gload_lds16(B + (size_t)(col0 + rblk + lr) * K + k0 + lc, &Bs[rblk * 32]);
        }
        __syncthreads();

        short8 af[2], bfr[4];
#pragma unroll
        for (int mi = 0; mi < 2; mi++)
            af[mi] = *(const short8*)&As[(wm * 32 + mi * 16 + (lane & 15)) * 32 + (lane >> 4) * 8];
#pragma unroll
        for (int nj = 0; nj < 4; nj++)
            bfr[nj] = *(const short8*)&Bs[(wn * 64 + nj * 16 + (lane & 15)) * 32 + (lane >> 4) * 8];
#pragma unroll
        for (int mi = 0; mi < 2; mi++)
#pragma unroll
            for (int nj = 0; nj < 4; nj++)
                acc[mi][nj] = __builtin_amdgcn_mfma_f32_16x16x32_bf16(
                    af[mi], bfr[nj], acc[mi][nj], 0, 0, 0);
        __syncthreads();
    }

    const int cr = (lane >> 4) * 4;
    const int cc = lane & 15;
#pragma unroll
    for (int mi = 0; mi < 2; mi++) {
#pragma unroll
        for (int nj = 0; nj < 4; nj++) {
            int c = col0 + wn * 64 + nj * 16 + cc;
#pragma unroll
            for (int r = 0; r < 4; r++) {
                int rr = row0 + wm * 32 + mi * 16 + cr + r;
                Cout[(size_t)rr * N + c] = acc[mi][nj][r];
            }
        }
    }
}

// ---------------------------------------------------------------------------
// prep: fused V-transpose + RoPE in one launch (independent slices of qkv).
//   blocks [0, 1024):  V transpose  qkv V slice (B,S,3,H,D) -> VT (B,H,D,S)
//   blocks [1024, 5120): RoPE in place on Q/K slices.
// Q scale = (1/8) * log2(e): scores land in log2 domain so the softmax
// exps are raw v_exp_f32 (fast_exp2), no per-exp multiply.
// ---------------------------------------------------------------------------
__global__ __launch_bounds__(256)
void prep_vtrans_rope(u16* __restrict__ qkv, u16* __restrict__ VT,
                      const int* __restrict__ pos) {
    const int bid = blockIdx.x;
    const int tid = threadIdx.x;

    if (bid < 1024) {
        // ---- V transpose: 64x64 LDS tile ----
        __shared__ u16 t[64][68];
        const int st = bid & 31, h = (bid >> 5) & 15, b = bid >> 9;
        const int bh = b * N_HEADS + h;
#pragma unroll
        for (int i = 0; i < 4; i++) {
            int e  = tid + i * 256;
            int sl = e >> 4;
            int c4 = e & 15;
            ushort4 v = *(const ushort4*)&qkv[((size_t)(b * S_LEN + st * 64 + sl) * 3 + 2) * D_MODEL
                                              + h * D_K + c4 * 4];
            *(ushort4*)&t[sl][c4 * 4] = v;
        }
        __syncthreads();
#pragma unroll
        for (int i = 0; i < 4; i++) {
            int e  = tid + i * 256;
            int d  = e >> 4;
            int s4 = e & 15;
            ushort4 o;
            o.x = t[s4 * 4 + 0][d];
            o.y = t[s4 * 4 + 1][d];
            o.z = t[s4 * 4 + 2][d];
            o.w = t[s4 * 4 + 3][d];
            *(ushort4*)&VT[((size_t)bh * D_K + d) * S_LEN + st * 64 + s4 * 4] = o;
        }
        return;
    }

    // ---- RoPE: thread handles 8 consecutive u16 = 4 rotation pairs ----
    int e  = (bid - 1024) * 256 + tid;      // 0 .. 1048575
    int j8 = e & 7;                          // 8-u16 chunk within head dim
    int h  = (e >> 3) & 15;
    int w  = (e >> 7) & 1;                   // 0=Q, 1=K
    int s  = (e >> 8) & 2047;
    int b  = e >> 19;

    float p  = (float)pos[s];
    float sc = (w == 0) ? 0.18033688011112042f : 1.0f;   // (1/8)*log2(e) for Q

    size_t base = (((size_t)(b * S_LEN + s) * 3 + w) * D_MODEL) + h * D_K + j8 * 8;
    ushort8 v = *(const ushort8*)&qkv[base];

    // inv_freq = 10000^(-j/32) = exp2(-j * log2(10000)/32)
    const float C = -0.41524101186092056f;   // -log2(10000)/32
#pragma unroll
    for (int jj = 0; jj < 4; jj++) {
        int j = j8 * 4 + jj;
        float ang = p * fast_exp2((float)j * C);
        float sn, cs;
        __sincosf(ang, &sn, &cs);
        float x1 = bf2f(v[2 * jj]);
        float x2 = bf2f(v[2 * jj + 1]);
        v[2 * jj]     = f2bf((x1 * cs - x2 * sn) * sc);
        v[2 * jj + 1] = f2bf((x1 * sn + x2 * cs) * sc);
    }
    *(ushort8*)&qkv[base] = v;
}

// ---------------------------------------------------------------------------
// One attention step (scores already in log2 domain; softmax via fast_exp2).
// S^T = K*Q^T; online softmax per lane (one query); O^T = V^T*P^T in regs
// (verified layout); T13 defer-max with THR=12 (P bounded by 2^12, f32/bf16
// headroom fine).  qsw = XOR-swizzled K/V chunk (T2, conflict-free).
// ---------------------------------------------------------------------------
__device__ __forceinline__ void attn_step(
    const u16* __restrict__ Ksc, const u16* __restrict__ Vsc,
    u16* __restrict__ Psw,
    short8 (&qf)[2], f32x4 (&acc)[4], float& mq, float& lq,
    int k0, int qw0, bool diag, int l15, int quad, int qsw)
{
    // ---- S^T = K*Q^T : s[nj] rows=keys nj*16+quad*4+r, col=query l15 ----
    f32x4 s[4] = {};
    __builtin_amdgcn_s_setprio(1);
#pragma unroll
    for (int kf = 0; kf < 2; kf++)
#pragma unroll
        for (int nj = 0; nj < 4; nj++) {
            short8 kfr = *(const short8*)&Ksc[kf * 2048 + (nj * 16 + l15) * 32 + qsw * 8];
            s[nj] = __builtin_amdgcn_mfma_f32_16x16x32_bf16(kfr, qf[kf], s[nj], 0, 0, 0);
        }
    __builtin_amdgcn_s_setprio(0);

    // ---- causal mask (diagonal tile only) ----
    if (diag) {
        const int row_g = qw0 + l15;
#pragma unroll
        for (int nj = 0; nj < 4; nj++)
#pragma unroll
            for (int r = 0; r < 4; r++) {
                int key_g = k0 + nj * 16 + quad * 4 + r;
                if (key_g > row_g) s[nj][r] = -INFINITY;
            }
    }

    // ---- online softmax: one query per lane, 16 keys in-lane ----
    float rmax = s[0][0];
#pragma unroll
    for (int nj = 0; nj < 4; nj++)
#pragma unroll
        for (int r = 0; r < 4; r++) rmax = fmaxf(rmax, s[nj][r]);
    rmax = fmaxf(rmax, __shfl_xor(rmax, 16, 64));
    rmax = fmaxf(rmax, __shfl_xor(rmax, 32, 64));

    // T13 defer-max: only touch mq / rescale O when the max actually grew.
    if (!__all(rmax <= mq + 12.f)) {
        float mn = fmaxf(mq, rmax);
        float alpha = fast_exp2(mq - mn);
        mq = mn;
        lq *= alpha;
#pragma unroll
        for (int nj = 0; nj < 4; nj++)
#pragma unroll
            for (int r = 0; r < 4; r++) acc[nj][r] *= alpha;
    }

    float rsum = 0.f;
#pragma unroll
    for (int nj = 0; nj < 4; nj++)
#pragma unroll
        for (int r = 0; r < 4; r++) {
            float p = fast_exp2(s[nj][r] - mq);
            s[nj][r] = p;
            rsum += p;
        }
    rsum += __shfl_xor(rsum, 16, 64);
    rsum += __shfl_xor(rsum, 32, 64);
    lq += rsum;

    // ---- P (bf16 pairs) -> wave-private LDS strip [query][key] ----
#pragma unroll
    for (int nj = 0; nj < 4; nj++) {
        u32 lo = ((u32)f2bf(s[nj][1]) << 16) | f2bf(s[nj][0]);
        u32 hi = ((u32)f2bf(s[nj][3]) << 16) | f2bf(s[nj][2]);
        uint2 pk; pk.x = lo; pk.y = hi;
        *(uint2*)&Psw[l15 * 68 + nj * 16 + quad * 4] = pk;
    }
    // same-wave LDS RAW -> compiler inserts lgkmcnt wait

    // ---- O^T += V^T*P^T : acc[nj] rows = d = nj*16+quad*4+r, col = q = l15 --
    __builtin_amdgcn_s_setprio(1);
#pragma unroll
    for (int kf = 0; kf < 2; kf++) {
        const u16* pp = &Psw[l15 * 68 + kf * 32 + quad * 8];
        uint2 plo = *(const uint2*)pp;
        uint2 phi = *(const uint2*)(pp + 4);
        u32 praw[4] = { plo.x, plo.y, phi.x, phi.y };
        short8 pf = *(const short8*)praw;
#pragma unroll
        for (int nj = 0; nj < 4; nj++) {
            short8 vf = *(const short8*)&Vsc[kf * 2048 + (nj * 16 + l15) * 32 + qsw * 8];
            acc[nj] = __builtin_amdgcn_mfma_f32_16x16x32_bf16(vf, pf, acc[nj], 0, 0, 0);
        }
    }
    __builtin_amdgcn_s_setprio(0);
}

// ---------------------------------------------------------------------------
// MFMA flash attention v8 (causal): KEY-SPLIT pairs + T2 swizzle + T14.
//
// vs v7 (46.6 us, conflicts 0, Occ 29%): v7's STAGE(kt) issued
// global_load_lds immediately before the barrier draining it -> full L2
// latency exposed every step.  T14 async-STAGE split (m214 v27, +17%):
// load tile kt+1 into REGISTERS at step start (latency hides under the
// current step's MFMA/softmax), ds_write after the read-barrier.  LDS
// stays 25 KB -> 4 blocks/CU kept; +16 VGPR.  Softmax in log2 domain.
// ---------------------------------------------------------------------------
__global__ __launch_bounds__(256)
void attn_mfma(const u16* __restrict__ qkv, const u16* __restrict__ VT,
               u16* __restrict__ out, float* __restrict__ partO,
               float* __restrict__ partML) {
    __shared__ u16 Ks[2][64 * 32];    // [kf d-chunk][key*32 + dL]  (swizzled)
    __shared__ u16 VsT[2][64 * 32];   // [kc key-chunk][d*32 + kL]  (swizzled)
    __shared__ u16 Ps[4][16 * 68];    // per-wave strip, reused by H then L

    const int tid  = threadIdx.x;
    const int lane = tid & 63;
    const int wv   = tid >> 6;

    // XCD-pinned decode (bijective over bid 0..1023):
    //   xcd=bid&7; idx=bid>>3; bh=xcd*4+(idx>>5); rem=idx&31; pr=rem>>1;
    //   role=rem&1.
    const int bid  = blockIdx.x;
    const int idx  = bid >> 3;
    const int bh   = (bid & 7) * 4 + (idx >> 5);
    const int rem  = idx & 31;
    const int pr   = rem >> 1;
    const int role = rem & 1;
    const int qtH  = 31 - pr;
    const int qtL  = pr;
    const int h    = bh & (N_HEADS - 1);
    const int b    = bh >> 4;

    const int l15  = lane & 15;
    const int quad = lane >> 4;
    const int qsw  = quad ^ ((l15 >> 1) & 3);       // swizzled read chunk
    const int qw0H = qtH * 64 + wv * 16;

    const size_t vtb = (size_t)bh * D_K * S_LEN;
    u16* Psw = &Ps[wv][0];
    const int lr  = lane >> 2;
    const int csw = ((lane & 3) ^ ((lane >> 3) & 3)) * 8;  // swizzled src chunk

    // prologue staging: async global->LDS (wave-uniform base, lane-linear)
    auto STAGE = [&](int kts) {
        const int k0s = kts * 64;
#pragma unroll
        for (int kf = 0; kf < 2; kf++)
            gload_lds16(qkv + ((size_t)(b * S_LEN + k0s + wv * 16 + lr) * 3 + 1) * D_MODEL
                            + h * D_K + kf * 32 + csw,
                        &Ks[kf][(wv * 16) * 32]);
#pragma unroll
        for (int kc = 0; kc < 2; kc++)
            gload_lds16(VT + vtb + (size_t)(wv * 16 + lr) * S_LEN + k0s + kc * 32 + csw,
                        &VsT[kc][(wv * 16) * 32]);
    };

    // T14 steady-state: load tile into regs early ...
    ushort8 kreg[2], vreg[2];
    auto REGLOAD = [&](int kts) {
        const int k0s = kts * 64;
#pragma unroll
        for (int kf = 0; kf < 2; kf++)
            kreg[kf] = *(const ushort8*)&qkv[((size_t)(b * S_LEN + k0s + wv * 16 + lr) * 3 + 1) * D_MODEL
                                             + h * D_K + kf * 32 + csw];
#pragma unroll
        for (int kc = 0; kc < 2; kc++)
            vreg[kc] = *(const ushort8*)&VT[vtb + (size_t)(wv * 16 + lr) * S_LEN + k0s + kc * 32 + csw];
    };
    // ... and commit to LDS after the read-barrier (same linear mapping as
    // gload_lds: wave base + lane*16B).
    auto LDSW = [&]() {
#pragma unroll
        for (int kf = 0; kf < 2; kf++)
            *(ushort8*)&Ks[kf][(wv * 16) * 32 + lane * 8] = kreg[kf];
#pragma unroll
        for (int kc = 0; kc < 2; kc++)
            *(ushort8*)&VsT[kc][(wv * 16) * 32 + lane * 8] = vreg[kc];
    };

    // ---- H q-tile: role 0 -> kt in [0,16]; role 1 -> kt in [17, qtH] ----
    short8 qfH[2];
#pragma unroll
    for (int kf = 0; kf < 2; kf++)
        qfH[kf] = *(const short8*)&qkv[((size_t)(b * S_LEN + qw0H + l15) * 3 + 0) * D_MODEL
                                       + h * D_K + kf * 32 + quad * 8];
    f32x4 accH[4] = {};
    float mqH = -INFINITY, lqH = 0.f;

    const int kbeg = role ? 17 : 0;
    const int kend = role ? qtH : 16;       // inclusive; role1 empty if qtH<17
    if (kbeg <= kend) {
        STAGE(kbeg);
        __syncthreads();                    // drain -> first tile resident
        for (int kt = kbeg; kt <= kend; kt++) {
            const bool more = kt < kend;    // block-uniform
            if (more) REGLOAD(kt + 1);      // latency hides under this step
            attn_step(&Ks[0][0], &VsT[0][0], Psw, qfH, accH, mqH, lqH,
                      kt * 64, qw0H, kt == qtH, l15, quad, qsw);
            __syncthreads();                // all waves done reading tile kt
            if (more) { LDSW(); __syncthreads(); }
        }
    }

    // ---- write H partial (unnormalized, defer-max state, log2 domain) ----
    {
        const size_t unit = (size_t)(bh * 16 + (qtH - 16)) * 2 + role;
        float* Od = partO + unit * 4096 + (size_t)(wv * 16 + l15) * 64;
#pragma unroll
        for (int nj = 0; nj < 4; nj++)
            *(f32x4*)&Od[nj * 16 + quad * 4] = accH[nj];
        if (quad == 0) {
            float* ML = partML + unit * 128;
            ML[wv * 16 + l15]      = mqH;
            ML[64 + wv * 16 + l15] = lqH;
        }
    }

    if (!role) return;

    // ---- L q-tile (role 1 only): kt 0..qtL, direct output ----
    const int qw0L = qtL * 64 + wv * 16;
    short8 qfL[2];
#pragma unroll
    for (int kf = 0; kf < 2; kf++)
        qfL[kf] = *(const short8*)&qkv[((size_t)(b * S_LEN + qw0L + l15) * 3 + 0) * D_MODEL
                                       + h * D_K + kf * 32 + quad * 8];
    f32x4 accL[4] = {};
    float mqL = -INFINITY, lqL = 0.f;

    STAGE(0);
    __syncthreads();
    for (int kt = 0; kt <= qtL; kt++) {
        const bool more = kt < qtL;
        if (more) REGLOAD(kt + 1);
        attn_step(&Ks[0][0], &VsT[0][0], Psw, qfL, accL, mqL, lqL,
                  kt * 64, qw0L, kt == qtL, l15, quad, qsw);
        __syncthreads();
        if (more) { LDSW(); __syncthreads(); }
    }

    float invl = 1.f / lqL;
#pragma unroll
    for (int nj = 0; nj < 4; nj++) {
        ushort4 o;
        o.x = f2bf(accL[nj][0] * invl); o.y = f2bf(accL[nj][1] * invl);
        o.z = f2bf(accL[nj][2] * invl); o.w = f2bf(accL[nj][3] * invl);
        *(ushort4*)&out[(size_t)(b * S_LEN + qw0L + l15) * D_MODEL
                        + h * D_K + nj * 16 + quad * 4] = o;
    }
}

// ---------------------------------------------------------------------------
// Merge the two key-range partials of each H q-tile and write bf16 output.
// m/l are in log2 domain: m*=max; f_i=exp2(m_i-m*);
// out = (f0*O0 + f1*O1) / (f0*l0 + f1*l1).
// ---------------------------------------------------------------------------
__global__ __launch_bounds__(256)
void attn_combine(const float* __restrict__ partO, const float* __restrict__ partML,
                  u16* __restrict__ out) {
    const int t16 = blockIdx.x & 15;
    const int bh  = blockIdx.x >> 4;
    const int h = bh & (N_HEADS - 1), b = bh >> 4;
    const int q0 = (t16 + 16) * 64;
    const int tid = threadIdx.x;
    const int q  = tid >> 2;          // 0..63
    const int d0 = (tid & 3) * 16;    // 0,16,32,48

    const size_t u0 = (size_t)(bh * 16 + t16) * 2;
    const float* O0 = partO + u0 * 4096;
    const float* O1 = O0 + 4096;
    const float* ML0 = partML + u0 * 128;
    const float* ML1 = ML0 + 128;

    float m0 = ML0[q], l0 = ML0[64 + q];
    float m1 = ML1[q], l1 = ML1[64 + q];
    float ms = fmaxf(m0, m1);
    float f0 = fast_exp2(m0 - ms), f1 = fast_exp2(m1 - ms);
    float inv = 1.f / (l0 * f0 + l1 * f1);
    f0 *= inv; f1 *= inv;
#pragma unroll
    for (int i = 0; i < 4; i++) {
        float4 a = *(const float4*)&O0[q * 64 + d0 + i * 4];
        float4 c = *(const float4*)&O1[q * 64 + d0 + i * 4];
        ushort4 o;
        o.x = f2bf(a.x * f0 + c.x * f1);
        o.y = f2bf(a.y * f0 + c.y * f1);
        o.z = f2bf(a.z * f0 + c.z * f1);
        o.w = f2bf(a.w * f0 + c.w * f1);
        *(ushort4*)&out[(size_t)(b * S_LEN + q0 + q) * D_MODEL + h * D_K + d0 + i * 4] = o;
    }
}

// ---------------------------------------------------------------------------
extern "C" void kernel_launch(void* const* d_in, const int* in_sizes, int n_in,
                              void* d_out, int out_size, void* d_ws, size_t ws_size,
                              hipStream_t stream) {
    const float* x    = (const float*)d_in[0];
    const int*   pos  = (const int*)d_in[1];
    const float* Wqkv = (const float*)d_in[2];
    const float* Wout = (const float*)d_in[3];
    float*       out  = (float*)d_out;

    const int M = B_SZ * S_LEN;   // 4096

    u16* qkvb = (u16*)d_ws;                            // 4096 x 3072
    u16* aob  = qkvb + (size_t)M * 3 * D_MODEL;        // 4096 x 1024
    u16* xb   = aob  + (size_t)M * D_MODEL;            // 4096 x 1024
    u16* wqb  = xb   + (size_t)M * D_MODEL;            // 3072 x 1024
    u16* wob  = wqb  + (size_t)3 * D_MODEL * D_MODEL;  // 1024 x 1024
    u16* vtb  = wob  + (size_t)D_MODEL * D_MODEL;      // 4096 x 1024
    float* partO  = (float*)(vtb + (size_t)M * D_MODEL);   // 1024 x 4096 f32
    float* partML = partO + (size_t)1024 * 4096;            // 1024 x 128 f32

    const int na4 = M * D_MODEL / 4;
    const int nb4 = 3 * D_MODEL * D_MODEL / 4;
    const int nc4 = D_MODEL * D_MODEL / 4;
    cast3_f32_bf16<<<(na4 + nb4 + nc4 + 255) / 256, 256, 0, stream>>>(
        x, xb, na4, Wqkv, wqb, nb4, Wout, wob, nc4);

    gemm_bt_mfma<true><<<dim3(3 * D_MODEL / 128, M / 128), 256, 0, stream>>>(
        xb, wqb, qkvb, M, 3 * D_MODEL, D_MODEL);

    // fused V-transpose (blocks 0..1023) + vectorized RoPE (blocks 1024..5119)
    prep_vtrans_rope<<<5120, 256, 0, stream>>>(qkvb, vtb, pos);

    attn_mfma<<<1024, 256, 0, stream>>>(qkvb, vtb, aob, partO, partML);
    attn_combine<<<512, 256, 0, stream>>>(partO, partML, aob);

    gemm_bt_mfma_64r<<<dim3(D_MODEL / 128, M / 64), 256, 0, stream>>>(
        aob, wob, out, M, D_MODEL, D_MODEL);
}

// Round 8
// 185.681 us; speedup vs baseline: 1.2358x; 1.0302x over previous
//
#include <hip/hip_runtime.h>
#include <hip/hip_bf16.h>
#include <math.h>

#define D_MODEL 1024
#define N_HEADS 16
#define D_K     64
#define S_LEN   2048
#define B_SZ    2

typedef unsigned short u16;
typedef unsigned int   u32;
using short8  = __attribute__((ext_vector_type(8))) short;
using ushort8 = __attribute__((ext_vector_type(8))) unsigned short;
using f32x4   = __attribute__((ext_vector_type(4))) float;

__device__ inline float bf2f(u16 u) { return __uint_as_float((u32)u << 16); }
__device__ inline u16 f2bf(float f) {
    __hip_bfloat16 h = __float2bfloat16(f);   // RNE
    return *(u16*)&h;
}
// raw v_exp_f32 (2^x).  __exp2f does not exist in HIP device code.
__device__ inline float fast_exp2(float x) { return __builtin_amdgcn_exp2f(x); }
__device__ inline void gload_lds16(const void* g, void* l) {
    __builtin_amdgcn_global_load_lds(
        (const __attribute__((address_space(1))) unsigned int*)g,
        (__attribute__((address_space(3))) unsigned int*)l, 16, 0, 0);
}

// ---------------------------------------------------------------------------
// fp32 -> bf16 cast for all three inputs in ONE launch (x | W_qkv | W_out).
// ---------------------------------------------------------------------------
__global__ __launch_bounds__(256)
void cast3_f32_bf16(const float* __restrict__ a, u16* __restrict__ ao, int na4,
                    const float* __restrict__ bsrc, u16* __restrict__ bo, int nb4,
                    const float* __restrict__ c, u16* __restrict__ co, int nc4) {
    int j = blockIdx.x * 256 + threadIdx.x;
    const float* src; u16* dst;
    if (j < na4) { src = a; dst = ao; }
    else {
        j -= na4;
        if (j < nb4) { src = bsrc; dst = bo; }
        else {
            j -= nb4;
            if (j >= nc4) return;
            src = c; dst = co;
        }
    }
    float4 v = ((const float4*)src)[j];
    ushort4 u;
    u.x = f2bf(v.x); u.y = f2bf(v.y); u.z = f2bf(v.z); u.w = f2bf(v.w);
    ((ushort4*)dst)[j] = u;
}

// ---------------------------------------------------------------------------
// bf16 MFMA GEMM, T3-minimal 2-PHASE: C[M][N] = A[M][K] * B[N][K]^T.
// vs R7 (43.6 us, MfmaUtil 23%, 600 TF @K=1024): the old loop was
// stage -> full-drain barrier -> compute -> barrier (1-phase).  Now K-tile
// k+1 is staged async into the other LDS buffer BEFORE computing tile k;
// ONE barrier per K-step (its vmcnt(0) drain retires the prefetch and
// fences the swap).  2ph/1ph = +18-30% measured at K=1024 (m230/m248).
// T2/T5 deliberately NOT added (both null at 2-phase per regime gate).
// LDS 32 KB -> still 5 blocks/CU capacity.  Fragments/C-write unchanged.
// ---------------------------------------------------------------------------
template <bool OUT_BF16>
__global__ __launch_bounds__(256)
void gemm_bt_mfma(const u16* __restrict__ A, const u16* __restrict__ B,
                  void* __restrict__ Cout, int M, int N, int K) {
    __shared__ u16 As[2][128 * 32];
    __shared__ u16 Bs[2][128 * 32];
    const int tid  = threadIdx.x;
    const int lane = tid & 63;
    const int wv   = tid >> 6;
    const int wm   = wv >> 1, wn = wv & 1;
    const int row0 = blockIdx.y * 128;
    const int col0 = blockIdx.x * 128;

    const int lr = lane >> 2;
    const int lc = (lane & 3) * 8;

    f32x4 acc[4][4] = {};

    auto STAGE = [&](int k0, int bf) {
#pragma unroll
        for (int t = 0; t < 2; t++) {
            int rblk = wv * 32 + t * 16;
            gload_lds16(A + (size_t)(row0 + rblk + lr) * K + k0 + lc, &As[bf][rblk * 32]);
            gload_lds16(B + (size_t)(col0 + rblk + lr) * K + k0 + lc, &Bs[bf][rblk * 32]);
        }
    };

    STAGE(0, 0);
    __syncthreads();            // vmcnt(0) drain -> tile 0 resident

    int cur = 0;
    for (int k0 = 0; k0 < K; k0 += 32) {
        if (k0 + 32 < K) STAGE(k0 + 32, cur ^ 1);   // prefetch next tile

        short8 af[4], bfr[4];
#pragma unroll
        for (int mi = 0; mi < 4; mi++)
            af[mi] = *(const short8*)&As[cur][(wm * 64 + mi * 16 + (lane & 15)) * 32 + (lane >> 4) * 8];
#pragma unroll
        for (int nj = 0; nj < 4; nj++)
            bfr[nj] = *(const short8*)&Bs[cur][(wn * 64 + nj * 16 + (lane & 15)) * 32 + (lane >> 4) * 8];
#pragma unroll
        for (int mi = 0; mi < 4; mi++)
#pragma unroll
            for (int nj = 0; nj < 4; nj++)
                acc[mi][nj] = __builtin_amdgcn_mfma_f32_16x16x32_bf16(
                    af[mi], bfr[nj], acc[mi][nj], 0, 0, 0);

        __syncthreads();        // retire prefetch + all waves done with buf[cur]
        cur ^= 1;
    }

    const int cr = (lane >> 4) * 4;
    const int cc = lane & 15;
#pragma unroll
    for (int mi = 0; mi < 4; mi++) {
#pragma unroll
        for (int nj = 0; nj < 4; nj++) {
            int c = col0 + wn * 64 + nj * 16 + cc;
#pragma unroll
            for (int r = 0; r < 4; r++) {
                int rr = row0 + wm * 64 + mi * 16 + cr + r;
                if (OUT_BF16)
                    ((u16*)Cout)[(size_t)rr * N + c] = f2bf(acc[mi][nj][r]);
                else
                    ((float*)Cout)[(size_t)rr * N + c] = acc[mi][nj][r];
            }
        }
    }
}

// ---------------------------------------------------------------------------
// 64x128-tile GEMM for gemm2 (M=4096, N=1024 -> 512 blocks = 2/CU), same
// 2-phase double-buffer conversion.  f32 output only.
// ---------------------------------------------------------------------------
__global__ __launch_bounds__(256)
void gemm_bt_mfma_64r(const u16* __restrict__ A, const u16* __restrict__ B,
                      float* __restrict__ Cout, int M, int N, int K) {
    __shared__ u16 As[2][64 * 32];
    __shared__ u16 Bs[2][128 * 32];
    const int tid  = threadIdx.x;
    const int lane = tid & 63;
    const int wv   = tid >> 6;
    const int wm   = wv >> 1, wn = wv & 1;
    const int row0 = blockIdx.y * 64;
    const int col0 = blockIdx.x * 128;

    const int lr = lane >> 2;
    const int lc = (lane & 3) * 8;

    f32x4 acc[2][4] = {};

    auto STAGE = [&](int k0, int bf) {
        gload_lds16(A + (size_t)(row0 + wv * 16 + lr) * K + k0 + lc, &As[bf][(wv * 16) * 32]);
#pragma unroll
        for (int t = 0; t < 2; t++) {
            int rblk = wv * 32 + t * 16;
            gload_lds16(B + (size_t)(col0 + rblk + lr) * K + k0 + lc, &Bs[bf][rblk * 32]);
        }
    };

    STAGE(0, 0);
    __syncthreads();

    int cur = 0;
    for (int k0 = 0; k0 < K; k0 += 32) {
        if (k0 + 32 < K) STAGE(k0 + 32, cur ^ 1);

        short8 af[2], bfr[4];
#pragma unroll
        for (int mi = 0; mi < 2; mi++)
            af[mi] = *(const short8*)&As[cur][(wm * 32 + mi * 16 + (lane & 15)) * 32 + (lane >> 4) * 8];
#pragma unroll
        for (int nj = 0; nj < 4; nj++)
            bfr[nj] = *(const short8*)&Bs[cur][(wn * 64 + nj * 16 + (lane & 15)) * 32 + (lane >> 4) * 8];
#pragma unroll
        for (int mi = 0; mi < 2; mi++)
#pragma unroll
            for (int nj = 0; nj < 4; nj++)
                acc[mi][nj] = __builtin_amdgcn_mfma_f32_16x16x32_bf16(
                    af[mi], bfr[nj], acc[mi][nj], 0, 0, 0);

        __syncthreads();
        cur ^= 1;
    }

    const int cr = (lane >> 4) * 4;
    const int cc = lane & 15;
#pragma unroll
    for (int mi = 0; mi < 2; mi++) {
#pragma unroll
        for (int nj = 0; nj < 4; nj++) {
            int c = col0 + wn * 64 + nj * 16 + cc;
#pragma unroll
            for (int r = 0; r < 4; r++) {
                int rr = row0 + wm * 32 + mi * 16 + cr + r;
                Cout[(size_t)rr * N + c] = acc[mi][nj][r];
            }
        }
    }
}

// ---------------------------------------------------------------------------
// prep: fused V-transpose + RoPE in one launch (independent slices of qkv).
//   blocks [0, 1024):  V transpose  qkv V slice (B,S,3,H,D) -> VT (B,H,D,S)
//   blocks [1024, 5120): RoPE in place on Q/K slices.
// Q scale = (1/8) * log2(e): scores land in log2 domain so the softmax
// exps are raw v_exp_f32 (fast_exp2), no per-exp multiply.
// ---------------------------------------------------------------------------
__global__ __launch_bounds__(256)
void prep_vtrans_rope(u16* __restrict__ qkv, u16* __restrict__ VT,
                      const int* __restrict__ pos) {
    const int bid = blockIdx.x;
    const int tid = threadIdx.x;

    if (bid < 1024) {
        // ---- V transpose: 64x64 LDS tile ----
        __shared__ u16 t[64][68];
        const int st = bid & 31, h = (bid >> 5) & 15, b = bid >> 9;
        const int bh = b * N_HEADS + h;
#pragma unroll
        for (int i = 0; i < 4; i++) {
            int e  = tid + i * 256;
            int sl = e >> 4;
            int c4 = e & 15;
            ushort4 v = *(const ushort4*)&qkv[((size_t)(b * S_LEN + st * 64 + sl) * 3 + 2) * D_MODEL
                                              + h * D_K + c4 * 4];
            *(ushort4*)&t[sl][c4 * 4] = v;
        }
        __syncthreads();
#pragma unroll
        for (int i = 0; i < 4; i++) {
            int e  = tid + i * 256;
            int d  = e >> 4;
            int s4 = e & 15;
            ushort4 o;
            o.x = t[s4 * 4 + 0][d];
            o.y = t[s4 * 4 + 1][d];
            o.z = t[s4 * 4 + 2][d];
            o.w = t[s4 * 4 + 3][d];
            *(ushort4*)&VT[((size_t)bh * D_K + d) * S_LEN + st * 64 + s4 * 4] = o;
        }
        return;
    }

    // ---- RoPE: thread handles 8 consecutive u16 = 4 rotation pairs ----
    int e  = (bid - 1024) * 256 + tid;      // 0 .. 1048575
    int j8 = e & 7;                          // 8-u16 chunk within head dim
    int h  = (e >> 3) & 15;
    int w  = (e >> 7) & 1;                   // 0=Q, 1=K
    int s  = (e >> 8) & 2047;
    int b  = e >> 19;

    float p  = (float)pos[s];
    float sc = (w == 0) ? 0.18033688011112042f : 1.0f;   // (1/8)*log2(e) for Q

    size_t base = (((size_t)(b * S_LEN + s) * 3 + w) * D_MODEL) + h * D_K + j8 * 8;
    ushort8 v = *(const ushort8*)&qkv[base];

    // inv_freq = 10000^(-j/32) = exp2(-j * log2(10000)/32)
    const float C = -0.41524101186092056f;   // -log2(10000)/32
#pragma unroll
    for (int jj = 0; jj < 4; jj++) {
        int j = j8 * 4 + jj;
        float ang = p * fast_exp2((float)j * C);
        float sn, cs;
        __sincosf(ang, &sn, &cs);
        float x1 = bf2f(v[2 * jj]);
        float x2 = bf2f(v[2 * jj + 1]);
        v[2 * jj]     = f2bf((x1 * cs - x2 * sn) * sc);
        v[2 * jj + 1] = f2bf((x1 * sn + x2 * cs) * sc);
    }
    *(ushort8*)&qkv[base] = v;
}

// ---------------------------------------------------------------------------
// One attention step (scores already in log2 domain; softmax via fast_exp2).
// S^T = K*Q^T; online softmax per lane (one query); O^T = V^T*P^T in regs
// (verified layout); T13 defer-max with THR=12 (P bounded by 2^12, f32/bf16
// headroom fine).  qsw = XOR-swizzled K/V chunk (T2, conflict-free).
// ---------------------------------------------------------------------------
__device__ __forceinline__ void attn_step(
    const u16* __restrict__ Ksc, const u16* __restrict__ Vsc,
    u16* __restrict__ Psw,
    short8 (&qf)[2], f32x4 (&acc)[4], float& mq, float& lq,
    int k0, int qw0, bool diag, int l15, int quad, int qsw)
{
    // ---- S^T = K*Q^T : s[nj] rows=keys nj*16+quad*4+r, col=query l15 ----
    f32x4 s[4] = {};
    __builtin_amdgcn_s_setprio(1);
#pragma unroll
    for (int kf = 0; kf < 2; kf++)
#pragma unroll
        for (int nj = 0; nj < 4; nj++) {
            short8 kfr = *(const short8*)&Ksc[kf * 2048 + (nj * 16 + l15) * 32 + qsw * 8];
            s[nj] = __builtin_amdgcn_mfma_f32_16x16x32_bf16(kfr, qf[kf], s[nj], 0, 0, 0);
        }
    __builtin_amdgcn_s_setprio(0);

    // ---- causal mask (diagonal tile only) ----
    if (diag) {
        const int row_g = qw0 + l15;
#pragma unroll
        for (int nj = 0; nj < 4; nj++)
#pragma unroll
            for (int r = 0; r < 4; r++) {
                int key_g = k0 + nj * 16 + quad * 4 + r;
                if (key_g > row_g) s[nj][r] = -INFINITY;
            }
    }

    // ---- online softmax: one query per lane, 16 keys in-lane ----
    float rmax = s[0][0];
#pragma unroll
    for (int nj = 0; nj < 4; nj++)
#pragma unroll
        for (int r = 0; r < 4; r++) rmax = fmaxf(rmax, s[nj][r]);
    rmax = fmaxf(rmax, __shfl_xor(rmax, 16, 64));
    rmax = fmaxf(rmax, __shfl_xor(rmax, 32, 64));

    // T13 defer-max: only touch mq / rescale O when the max actually grew.
    if (!__all(rmax <= mq + 12.f)) {
        float mn = fmaxf(mq, rmax);
        float alpha = fast_exp2(mq - mn);
        mq = mn;
        lq *= alpha;
#pragma unroll
        for (int nj = 0; nj < 4; nj++)
#pragma unroll
            for (int r = 0; r < 4; r++) acc[nj][r] *= alpha;
    }

    float rsum = 0.f;
#pragma unroll
    for (int nj = 0; nj < 4; nj++)
#pragma unroll
        for (int r = 0; r < 4; r++) {
            float p = fast_exp2(s[nj][r] - mq);
            s[nj][r] = p;
            rsum += p;
        }
    rsum += __shfl_xor(rsum, 16, 64);
    rsum += __shfl_xor(rsum, 32, 64);
    lq += rsum;

    // ---- P (bf16 pairs) -> wave-private LDS strip [query][key] ----
#pragma unroll
    for (int nj = 0; nj < 4; nj++) {
        u32 lo = ((u32)f2bf(s[nj][1]) << 16) | f2bf(s[nj][0]);
        u32 hi = ((u32)f2bf(s[nj][3]) << 16) | f2bf(s[nj][2]);
        uint2 pk; pk.x = lo; pk.y = hi;
        *(uint2*)&Psw[l15 * 68 + nj * 16 + quad * 4] = pk;
    }
    // same-wave LDS RAW -> compiler inserts lgkmcnt wait

    // ---- O^T += V^T*P^T : acc[nj] rows = d = nj*16+quad*4+r, col = q = l15 --
    __builtin_amdgcn_s_setprio(1);
#pragma unroll
    for (int kf = 0; kf < 2; kf++) {
        const u16* pp = &Psw[l15 * 68 + kf * 32 + quad * 8];
        uint2 plo = *(const uint2*)pp;
        uint2 phi = *(const uint2*)(pp + 4);
        u32 praw[4] = { plo.x, plo.y, phi.x, phi.y };
        short8 pf = *(const short8*)praw;
#pragma unroll
        for (int nj = 0; nj < 4; nj++) {
            short8 vf = *(const short8*)&Vsc[kf * 2048 + (nj * 16 + l15) * 32 + qsw * 8];
            acc[nj] = __builtin_amdgcn_mfma_f32_16x16x32_bf16(vf, pf, acc[nj], 0, 0, 0);
        }
    }
    __builtin_amdgcn_s_setprio(0);
}

// ---------------------------------------------------------------------------
// MFMA flash attention v8 (causal): KEY-SPLIT pairs + T2 swizzle + T14.
// (unchanged from R7 -- verified; attn now < 43 us)
// ---------------------------------------------------------------------------
__global__ __launch_bounds__(256)
void attn_mfma(const u16* __restrict__ qkv, const u16* __restrict__ VT,
               u16* __restrict__ out, float* __restrict__ partO,
               float* __restrict__ partML) {
    __shared__ u16 Ks[2][64 * 32];    // [kf d-chunk][key*32 + dL]  (swizzled)
    __shared__ u16 VsT[2][64 * 32];   // [kc key-chunk][d*32 + kL]  (swizzled)
    __shared__ u16 Ps[4][16 * 68];    // per-wave strip, reused by H then L

    const int tid  = threadIdx.x;
    const int lane = tid & 63;
    const int wv   = tid >> 6;

    // XCD-pinned decode (bijective over bid 0..1023):
    //   xcd=bid&7; idx=bid>>3; bh=xcd*4+(idx>>5); rem=idx&31; pr=rem>>1;
    //   role=rem&1.
    const int bid  = blockIdx.x;
    const int idx  = bid >> 3;
    const int bh   = (bid & 7) * 4 + (idx >> 5);
    const int rem  = idx & 31;
    const int pr   = rem >> 1;
    const int role = rem & 1;
    const int qtH  = 31 - pr;
    const int qtL  = pr;
    const int h    = bh & (N_HEADS - 1);
    const int b    = bh >> 4;

    const int l15  = lane & 15;
    const int quad = lane >> 4;
    const int qsw  = quad ^ ((l15 >> 1) & 3);       // swizzled read chunk
    const int qw0H = qtH * 64 + wv * 16;

    const size_t vtb = (size_t)bh * D_K * S_LEN;
    u16* Psw = &Ps[wv][0];
    const int lr  = lane >> 2;
    const int csw = ((lane & 3) ^ ((lane >> 3) & 3)) * 8;  // swizzled src chunk

    // prologue staging: async global->LDS (wave-uniform base, lane-linear)
    auto STAGE = [&](int kts) {
        const int k0s = kts * 64;
#pragma unroll
        for (int kf = 0; kf < 2; kf++)
            gload_lds16(qkv + ((size_t)(b * S_LEN + k0s + wv * 16 + lr) * 3 + 1) * D_MODEL
                            + h * D_K + kf * 32 + csw,
                        &Ks[kf][(wv * 16) * 32]);
#pragma unroll
        for (int kc = 0; kc < 2; kc++)
            gload_lds16(VT + vtb + (size_t)(wv * 16 + lr) * S_LEN + k0s + kc * 32 + csw,
                        &VsT[kc][(wv * 16) * 32]);
    };

    // T14 steady-state: load tile into regs early ...
    ushort8 kreg[2], vreg[2];
    auto REGLOAD = [&](int kts) {
        const int k0s = kts * 64;
#pragma unroll
        for (int kf = 0; kf < 2; kf++)
            kreg[kf] = *(const ushort8*)&qkv[((size_t)(b * S_LEN + k0s + wv * 16 + lr) * 3 + 1) * D_MODEL
                                             + h * D_K + kf * 32 + csw];
#pragma unroll
        for (int kc = 0; kc < 2; kc++)
            vreg[kc] = *(const ushort8*)&VT[vtb + (size_t)(wv * 16 + lr) * S_LEN + k0s + kc * 32 + csw];
    };
    // ... and commit to LDS after the read-barrier (same linear mapping as
    // gload_lds: wave base + lane*16B).
    auto LDSW = [&]() {
#pragma unroll
        for (int kf = 0; kf < 2; kf++)
            *(ushort8*)&Ks[kf][(wv * 16) * 32 + lane * 8] = kreg[kf];
#pragma unroll
        for (int kc = 0; kc < 2; kc++)
            *(ushort8*)&VsT[kc][(wv * 16) * 32 + lane * 8] = vreg[kc];
    };

    // ---- H q-tile: role 0 -> kt in [0,16]; role 1 -> kt in [17, qtH] ----
    short8 qfH[2];
#pragma unroll
    for (int kf = 0; kf < 2; kf++)
        qfH[kf] = *(const short8*)&qkv[((size_t)(b * S_LEN + qw0H + l15) * 3 + 0) * D_MODEL
                                       + h * D_K + kf * 32 + quad * 8];
    f32x4 accH[4] = {};
    float mqH = -INFINITY, lqH = 0.f;

    const int kbeg = role ? 17 : 0;
    const int kend = role ? qtH : 16;       // inclusive; role1 empty if qtH<17
    if (kbeg <= kend) {
        STAGE(kbeg);
        __syncthreads();                    // drain -> first tile resident
        for (int kt = kbeg; kt <= kend; kt++) {
            const bool more = kt < kend;    // block-uniform
            if (more) REGLOAD(kt + 1);      // latency hides under this step
            attn_step(&Ks[0][0], &VsT[0][0], Psw, qfH, accH, mqH, lqH,
                      kt * 64, qw0H, kt == qtH, l15, quad, qsw);
            __syncthreads();                // all waves done reading tile kt
            if (more) { LDSW(); __syncthreads(); }
        }
    }

    // ---- write H partial (unnormalized, defer-max state, log2 domain) ----
    {
        const size_t unit = (size_t)(bh * 16 + (qtH - 16)) * 2 + role;
        float* Od = partO + unit * 4096 + (size_t)(wv * 16 + l15) * 64;
#pragma unroll
        for (int nj = 0; nj < 4; nj++)
            *(f32x4*)&Od[nj * 16 + quad * 4] = accH[nj];
        if (quad == 0) {
            float* ML = partML + unit * 128;
            ML[wv * 16 + l15]      = mqH;
            ML[64 + wv * 16 + l15] = lqH;
        }
    }

    if (!role) return;

    // ---- L q-tile (role 1 only): kt 0..qtL, direct output ----
    const int qw0L = qtL * 64 + wv * 16;
    short8 qfL[2];
#pragma unroll
    for (int kf = 0; kf < 2; kf++)
        qfL[kf] = *(const short8*)&qkv[((size_t)(b * S_LEN + qw0L + l15) * 3 + 0) * D_MODEL
                                       + h * D_K + kf * 32 + quad * 8];
    f32x4 accL[4] = {};
    float mqL = -INFINITY, lqL = 0.f;

    STAGE(0);
    __syncthreads();
    for (int kt = 0; kt <= qtL; kt++) {
        const bool more = kt < qtL;
        if (more) REGLOAD(kt + 1);
        attn_step(&Ks[0][0], &VsT[0][0], Psw, qfL, accL, mqL, lqL,
                  kt * 64, qw0L, kt == qtL, l15, quad, qsw);
        __syncthreads();
        if (more) { LDSW(); __syncthreads(); }
    }

    float invl = 1.f / lqL;
#pragma unroll
    for (int nj = 0; nj < 4; nj++) {
        ushort4 o;
        o.x = f2bf(accL[nj][0] * invl); o.y = f2bf(accL[nj][1] * invl);
        o.z = f2bf(accL[nj][2] * invl); o.w = f2bf(accL[nj][3] * invl);
        *(ushort4*)&out[(size_t)(b * S_LEN + qw0L + l15) * D_MODEL
                        + h * D_K + nj * 16 + quad * 4] = o;
    }
}

// ---------------------------------------------------------------------------
// Merge the two key-range partials of each H q-tile and write bf16 output.
// m/l are in log2 domain: m*=max; f_i=exp2(m_i-m*);
// out = (f0*O0 + f1*O1) / (f0*l0 + f1*l1).
// ---------------------------------------------------------------------------
__global__ __launch_bounds__(256)
void attn_combine(const float* __restrict__ partO, const float* __restrict__ partML,
                  u16* __restrict__ out) {
    const int t16 = blockIdx.x & 15;
    const int bh  = blockIdx.x >> 4;
    const int h = bh & (N_HEADS - 1), b = bh >> 4;
    const int q0 = (t16 + 16) * 64;
    const int tid = threadIdx.x;
    const int q  = tid >> 2;          // 0..63
    const int d0 = (tid & 3) * 16;    // 0,16,32,48

    const size_t u0 = (size_t)(bh * 16 + t16) * 2;
    const float* O0 = partO + u0 * 4096;
    const float* O1 = O0 + 4096;
    const float* ML0 = partML + u0 * 128;
    const float* ML1 = ML0 + 128;

    float m0 = ML0[q], l0 = ML0[64 + q];
    float m1 = ML1[q], l1 = ML1[64 + q];
    float ms = fmaxf(m0, m1);
    float f0 = fast_exp2(m0 - ms), f1 = fast_exp2(m1 - ms);
    float inv = 1.f / (l0 * f0 + l1 * f1);
    f0 *= inv; f1 *= inv;
#pragma unroll
    for (int i = 0; i < 4; i++) {
        float4 a = *(const float4*)&O0[q * 64 + d0 + i * 4];
        float4 c = *(const float4*)&O1[q * 64 + d0 + i * 4];
        ushort4 o;
        o.x = f2bf(a.x * f0 + c.x * f1);
        o.y = f2bf(a.y * f0 + c.y * f1);
        o.z = f2bf(a.z * f0 + c.z * f1);
        o.w = f2bf(a.w * f0 + c.w * f1);
        *(ushort4*)&out[(size_t)(b * S_LEN + q0 + q) * D_MODEL + h * D_K + d0 + i * 4] = o;
    }
}

// ---------------------------------------------------------------------------
extern "C" void kernel_launch(void* const* d_in, const int* in_sizes, int n_in,
                              void* d_out, int out_size, void* d_ws, size_t ws_size,
                              hipStream_t stream) {
    const float* x    = (const float*)d_in[0];
    const int*   pos  = (const int*)d_in[1];
    const float* Wqkv = (const float*)d_in[2];
    const float* Wout = (const float*)d_in[3];
    float*       out  = (float*)d_out;

    const int M = B_SZ * S_LEN;   // 4096

    u16* qkvb = (u16*)d_ws;                            // 4096 x 3072
    u16* aob  = qkvb + (size_t)M * 3 * D_MODEL;        // 4096 x 1024
    u16* xb   = aob  + (size_t)M * D_MODEL;            // 4096 x 1024
    u16* wqb  = xb   + (size_t)M * D_MODEL;            // 3072 x 1024
    u16* wob  = wqb  + (size_t)3 * D_MODEL * D_MODEL;  // 1024 x 1024
    u16* vtb  = wob  + (size_t)D_MODEL * D_MODEL;      // 4096 x 1024
    float* partO  = (float*)(vtb + (size_t)M * D_MODEL);   // 1024 x 4096 f32
    float* partML = partO + (size_t)1024 * 4096;            // 1024 x 128 f32

    const int na4 = M * D_MODEL / 4;
    const int nb4 = 3 * D_MODEL * D_MODEL / 4;
    const int nc4 = D_MODEL * D_MODEL / 4;
    cast3_f32_bf16<<<(na4 + nb4 + nc4 + 255) / 256, 256, 0, stream>>>(
        x, xb, na4, Wqkv, wqb, nb4, Wout, wob, nc4);

    gemm_bt_mfma<true><<<dim3(3 * D_MODEL / 128, M / 128), 256, 0, stream>>>(
        xb, wqb, qkvb, M, 3 * D_MODEL, D_MODEL);

    // fused V-transpose (blocks 0..1023) + vectorized RoPE (blocks 1024..5119)
    prep_vtrans_rope<<<5120, 256, 0, stream>>>(qkvb, vtb, pos);

    attn_mfma<<<1024, 256, 0, stream>>>(qkvb, vtb, aob, partO, partML);
    attn_combine<<<512, 256, 0, stream>>>(partO, partML, aob);

    gemm_bt_mfma_64r<<<dim3(D_MODEL / 128, M / 64), 256, 0, stream>>>(
        aob, wob, out, M, D_MODEL, D_MODEL);
}

// Round 10
// 183.252 us; speedup vs baseline: 1.2522x; 1.0133x over previous
//
#include <hip/hip_runtime.h>
#include <hip/hip_bf16.h>
#include <math.h>

#define D_MODEL 1024
#define N_HEADS 16
#define D_K     64
#define S_LEN   2048
#define B_SZ    2

typedef unsigned short u16;
typedef unsigned int   u32;
using short8  = __attribute__((ext_vector_type(8))) short;
using ushort8 = __attribute__((ext_vector_type(8))) unsigned short;
using f32x4   = __attribute__((ext_vector_type(4))) float;

__device__ inline float bf2f(u16 u) { return __uint_as_float((u32)u << 16); }
__device__ inline u16 f2bf(float f) {
    __hip_bfloat16 h = __float2bfloat16(f);   // RNE
    return *(u16*)&h;
}
// raw v_exp_f32 (2^x).  __exp2f does not exist in HIP device code.
__device__ inline float fast_exp2(float x) { return __builtin_amdgcn_exp2f(x); }
__device__ inline void gload_lds16(const void* g, void* l) {
    __builtin_amdgcn_global_load_lds(
        (const __attribute__((address_space(1))) unsigned int*)g,
        (__attribute__((address_space(3))) unsigned int*)l, 16, 0, 0);
}

// ---------------------------------------------------------------------------
// fp32 -> bf16 cast for all three inputs in ONE launch (x | W_qkv | W_out).
// ---------------------------------------------------------------------------
__global__ __launch_bounds__(256)
void cast3_f32_bf16(const float* __restrict__ a, u16* __restrict__ ao, int na4,
                    const float* __restrict__ bsrc, u16* __restrict__ bo, int nb4,
                    const float* __restrict__ c, u16* __restrict__ co, int nc4) {
    int j = blockIdx.x * 256 + threadIdx.x;
    const float* src; u16* dst;
    if (j < na4) { src = a; dst = ao; }
    else {
        j -= na4;
        if (j < nb4) { src = bsrc; dst = bo; }
        else {
            j -= nb4;
            if (j >= nc4) return;
            src = c; dst = co;
        }
    }
    float4 v = ((const float4*)src)[j];
    ushort4 u;
    u.x = f2bf(v.x); u.y = f2bf(v.y); u.z = f2bf(v.z); u.w = f2bf(v.w);
    ((ushort4*)dst)[j] = u;
}

// ---------------------------------------------------------------------------
// gemm1 with FUSED RoPE epilogue: qkv = x * Wqkv^T, then rotate Q/K pairs
// in-register before the bf16 store (saves the separate 67 MB RoPE pass).
// 2-phase double-buffered staging (verified R8).  Rotation: pair (2j,2j+1)
// lives in adjacent lanes (col parity == lane parity) -> one __shfl_xor.
// Q additionally scaled by (1/8)*log2(e) so attention scores land in the
// log2 domain.  w = c>>10 (0=Q rot+scale, 1=K rot, 2=V passthrough) is
// block-uniform (1024 % 128 == 0).
// ---------------------------------------------------------------------------
__global__ __launch_bounds__(256)
void gemm_qkv_rope(const u16* __restrict__ A, const u16* __restrict__ B,
                   u16* __restrict__ Cout, const int* __restrict__ pos,
                   int M, int N, int K) {
    __shared__ u16 As[2][128 * 32];
    __shared__ u16 Bs[2][128 * 32];
    const int tid  = threadIdx.x;
    const int lane = tid & 63;
    const int wv   = tid >> 6;
    const int wm   = wv >> 1, wn = wv & 1;
    const int row0 = blockIdx.y * 128;
    const int col0 = blockIdx.x * 128;

    const int lr = lane >> 2;
    const int lc = (lane & 3) * 8;

    f32x4 acc[4][4] = {};

    auto STAGE = [&](int k0, int bf) {
#pragma unroll
        for (int t = 0; t < 2; t++) {
            int rblk = wv * 32 + t * 16;
            gload_lds16(A + (size_t)(row0 + rblk + lr) * K + k0 + lc, &As[bf][rblk * 32]);
            gload_lds16(B + (size_t)(col0 + rblk + lr) * K + k0 + lc, &Bs[bf][rblk * 32]);
        }
    };

    STAGE(0, 0);
    __syncthreads();

    int cur = 0;
    for (int k0 = 0; k0 < K; k0 += 32) {
        if (k0 + 32 < K) STAGE(k0 + 32, cur ^ 1);

        short8 af[4], bfr[4];
#pragma unroll
        for (int mi = 0; mi < 4; mi++)
            af[mi] = *(const short8*)&As[cur][(wm * 64 + mi * 16 + (lane & 15)) * 32 + (lane >> 4) * 8];
#pragma unroll
        for (int nj = 0; nj < 4; nj++)
            bfr[nj] = *(const short8*)&Bs[cur][(wn * 64 + nj * 16 + (lane & 15)) * 32 + (lane >> 4) * 8];
#pragma unroll
        for (int mi = 0; mi < 4; mi++)
#pragma unroll
            for (int nj = 0; nj < 4; nj++)
                acc[mi][nj] = __builtin_amdgcn_mfma_f32_16x16x32_bf16(
                    af[mi], bfr[nj], acc[mi][nj], 0, 0, 0);

        __syncthreads();
        cur ^= 1;
    }

    // ---- epilogue: fused RoPE ----
    const int cr = (lane >> 4) * 4;
    const int cc = lane & 15;
    const int cb = col0 + wn * 64 + cc;       // this lane's column base
    const int w  = cb >> 10;                  // 0=Q 1=K 2=V (block-uniform)
    const float CLOG = -0.41524101186092056f; // -log2(10000)/32
    const float qsc  = (w == 0) ? 0.18033688011112042f : 1.0f; // (1/8)*log2e
    float invf[4];
#pragma unroll
    for (int nj = 0; nj < 4; nj++)
        invf[nj] = fast_exp2((float)(((cb + nj * 16) & 63) >> 1) * CLOG);

#pragma unroll
    for (int mi = 0; mi < 4; mi++) {
#pragma unroll
        for (int r = 0; r < 4; r++) {
            int rr = row0 + wm * 64 + mi * 16 + cr + r;
            float p = (w == 2) ? 0.f : (float)pos[rr & (S_LEN - 1)];
#pragma unroll
            for (int nj = 0; nj < 4; nj++) {
                float v = acc[mi][nj][r];
                float partner = __shfl_xor(v, 1, 64);
                float res;
                if (w == 2) {
                    res = v;
                } else {
                    float sn, cs;
                    __sincosf(p * invf[nj], &sn, &cs);
                    // even col: x1=v, x2=partner ; odd col: x1=partner, x2=v
                    res = ((cc & 1) ? (partner * sn + v * cs)
                                    : (v * cs - partner * sn)) * qsc;
                }
                Cout[(size_t)rr * N + cb + nj * 16] = f2bf(res);
            }
        }
    }
}

// ---------------------------------------------------------------------------
// 64x128-tile 2-phase GEMM for gemm2 (M=4096, N=1024 -> 512 blocks = 2/CU).
// f32 output.  (verified R8)
// ---------------------------------------------------------------------------
__global__ __launch_bounds__(256)
void gemm_bt_mfma_64r(const u16* __restrict__ A, const u16* __restrict__ B,
                      float* __restrict__ Cout, int M, int N, int K) {
    __shared__ u16 As[2][64 * 32];
    __shared__ u16 Bs[2][128 * 32];
    const int tid  = threadIdx.x;
    const int lane = tid & 63;
    const int wv   = tid >> 6;
    const int wm   = wv >> 1, wn = wv & 1;
    const int row0 = blockIdx.y * 64;
    const int col0 = blockIdx.x * 128;

    const int lr = lane >> 2;
    const int lc = (lane & 3) * 8;

    f32x4 acc[2][4] = {};

    auto STAGE = [&](int k0, int bf) {
        gload_lds16(A + (size_t)(row0 + wv * 16 + lr) * K + k0 + lc, &As[bf][(wv * 16) * 32]);
#pragma unroll
        for (int t = 0; t < 2; t++) {
            int rblk = wv * 32 + t * 16;
            gload_lds16(B + (size_t)(col0 + rblk + lr) * K + k0 + lc, &Bs[bf][rblk * 32]);
        }
    };

    STAGE(0, 0);
    __syncthreads();

    int cur = 0;
    for (int k0 = 0; k0 < K; k0 += 32) {
        if (k0 + 32 < K) STAGE(k0 + 32, cur ^ 1);

        short8 af[2], bfr[4];
#pragma unroll
        for (int mi = 0; mi < 2; mi++)
            af[mi] = *(const short8*)&As[cur][(wm * 32 + mi * 16 + (lane & 15)) * 32 + (lane >> 4) * 8];
#pragma unroll
        for (int nj = 0; nj < 4; nj++)
            bfr[nj] = *(const short8*)&Bs[cur][(wn * 64 + nj * 16 + (lane & 15)) * 32 + (lane >> 4) * 8];
#pragma unroll
        for (int mi = 0; mi < 2; mi++)
#pragma unroll
            for (int nj = 0; nj < 4; nj++)
                acc[mi][nj] = __builtin_amdgcn_mfma_f32_16x16x32_bf16(
                    af[mi], bfr[nj], acc[mi][nj], 0, 0, 0);

        __syncthreads();
        cur ^= 1;
    }

    const int cr = (lane >> 4) * 4;
    const int cc = lane & 15;
#pragma unroll
    for (int mi = 0; mi < 2; mi++) {
#pragma unroll
        for (int nj = 0; nj < 4; nj++) {
            int c = col0 + wn * 64 + nj * 16 + cc;
#pragma unroll
            for (int r = 0; r < 4; r++) {
                int rr = row0 + wm * 32 + mi * 16 + cr + r;
                Cout[(size_t)rr * N + c] = acc[mi][nj][r];
            }
        }
    }
}

// ---------------------------------------------------------------------------
// V transpose only (RoPE now fused into gemm1's epilogue).
// qkv V slice (B,S,3,H,D) -> VT (B,H,D,S).  64x64 LDS tile.
// ---------------------------------------------------------------------------
__global__ __launch_bounds__(256)
void vtrans(const u16* __restrict__ qkv, u16* __restrict__ VT) {
    __shared__ u16 t[64][68];
    const int bid = blockIdx.x;
    const int tid = threadIdx.x;
    const int st = bid & 31, h = (bid >> 5) & 15, b = bid >> 9;
    const int bh = b * N_HEADS + h;
#pragma unroll
    for (int i = 0; i < 4; i++) {
        int e  = tid + i * 256;
        int sl = e >> 4;
        int c4 = e & 15;
        ushort4 v = *(const ushort4*)&qkv[((size_t)(b * S_LEN + st * 64 + sl) * 3 + 2) * D_MODEL
                                          + h * D_K + c4 * 4];
        *(ushort4*)&t[sl][c4 * 4] = v;
    }
    __syncthreads();
#pragma unroll
    for (int i = 0; i < 4; i++) {
        int e  = tid + i * 256;
        int d  = e >> 4;
        int s4 = e & 15;
        ushort4 o;
        o.x = t[s4 * 4 + 0][d];
        o.y = t[s4 * 4 + 1][d];
        o.z = t[s4 * 4 + 2][d];
        o.w = t[s4 * 4 + 3][d];
        *(ushort4*)&VT[((size_t)bh * D_K + d) * S_LEN + st * 64 + s4 * 4] = o;
    }
}

// ---------------------------------------------------------------------------
// One attention step (scores in log2 domain; softmax via fast_exp2).
// S^T = K*Q^T; online softmax per lane (one query); O^T = V^T*P^T in regs;
// T13 defer-max THR=12.  Max/sum reductions are pairwise TREES (the old
// serial 16-deep fmax/add chains were un-reassociable latency).
// ---------------------------------------------------------------------------
__device__ __forceinline__ void attn_step(
    const u16* __restrict__ Ksc, const u16* __restrict__ Vsc,
    u16* __restrict__ Psw,
    short8 (&qf)[2], f32x4 (&acc)[4], float& mq, float& lq,
    int k0, int qw0, bool diag, int l15, int quad, int qsw)
{
    // ---- S^T = K*Q^T : s[nj] rows=keys nj*16+quad*4+r, col=query l15 ----
    f32x4 s[4] = {};
    __builtin_amdgcn_s_setprio(1);
#pragma unroll
    for (int kf = 0; kf < 2; kf++)
#pragma unroll
        for (int nj = 0; nj < 4; nj++) {
            short8 kfr = *(const short8*)&Ksc[kf * 2048 + (nj * 16 + l15) * 32 + qsw * 8];
            s[nj] = __builtin_amdgcn_mfma_f32_16x16x32_bf16(kfr, qf[kf], s[nj], 0, 0, 0);
        }
    __builtin_amdgcn_s_setprio(0);

    // ---- causal mask (diagonal tile only) ----
    if (diag) {
        const int row_g = qw0 + l15;
#pragma unroll
        for (int nj = 0; nj < 4; nj++)
#pragma unroll
            for (int r = 0; r < 4; r++) {
                int key_g = k0 + nj * 16 + quad * 4 + r;
                if (key_g > row_g) s[nj][r] = -INFINITY;
            }
    }

    // ---- online softmax: tree max ----
    float mx[4];
#pragma unroll
    for (int nj = 0; nj < 4; nj++)
        mx[nj] = fmaxf(fmaxf(s[nj][0], s[nj][1]), fmaxf(s[nj][2], s[nj][3]));
    float rmax = fmaxf(fmaxf(mx[0], mx[1]), fmaxf(mx[2], mx[3]));
    rmax = fmaxf(rmax, __shfl_xor(rmax, 16, 64));
    rmax = fmaxf(rmax, __shfl_xor(rmax, 32, 64));

    // T13 defer-max: only touch mq / rescale O when the max actually grew.
    if (!__all(rmax <= mq + 12.f)) {
        float mn = fmaxf(mq, rmax);
        float alpha = fast_exp2(mq - mn);
        mq = mn;
        lq *= alpha;
#pragma unroll
        for (int nj = 0; nj < 4; nj++)
#pragma unroll
            for (int r = 0; r < 4; r++) acc[nj][r] *= alpha;
    }

    // ---- exp + tree sum ----
    float rs[4];
#pragma unroll
    for (int nj = 0; nj < 4; nj++) {
        float p0 = fast_exp2(s[nj][0] - mq);
        float p1 = fast_exp2(s[nj][1] - mq);
        float p2 = fast_exp2(s[nj][2] - mq);
        float p3 = fast_exp2(s[nj][3] - mq);
        s[nj][0] = p0; s[nj][1] = p1; s[nj][2] = p2; s[nj][3] = p3;
        rs[nj] = (p0 + p1) + (p2 + p3);
    }
    float rsum = (rs[0] + rs[1]) + (rs[2] + rs[3]);
    rsum += __shfl_xor(rsum, 16, 64);
    rsum += __shfl_xor(rsum, 32, 64);
    lq += rsum;

    // ---- P (bf16 pairs) -> wave-private LDS strip [query][key] ----
#pragma unroll
    for (int nj = 0; nj < 4; nj++) {
        u32 lo = ((u32)f2bf(s[nj][1]) << 16) | f2bf(s[nj][0]);
        u32 hi = ((u32)f2bf(s[nj][3]) << 16) | f2bf(s[nj][2]);
        uint2 pk; pk.x = lo; pk.y = hi;
        *(uint2*)&Psw[l15 * 68 + nj * 16 + quad * 4] = pk;
    }
    // same-wave LDS RAW -> compiler inserts lgkmcnt wait

    // ---- O^T += V^T*P^T : acc[nj] rows = d = nj*16+quad*4+r, col = q = l15 --
    __builtin_amdgcn_s_setprio(1);
#pragma unroll
    for (int kf = 0; kf < 2; kf++) {
        const u16* pp = &Psw[l15 * 68 + kf * 32 + quad * 8];
        uint2 plo = *(const uint2*)pp;
        uint2 phi = *(const uint2*)(pp + 4);
        u32 praw[4] = { plo.x, plo.y, phi.x, phi.y };
        short8 pf = *(const short8*)praw;
#pragma unroll
        for (int nj = 0; nj < 4; nj++) {
            short8 vf = *(const short8*)&Vsc[kf * 2048 + (nj * 16 + l15) * 32 + qsw * 8];
            acc[nj] = __builtin_amdgcn_mfma_f32_16x16x32_bf16(vf, pf, acc[nj], 0, 0, 0);
        }
    }
    __builtin_amdgcn_s_setprio(0);
}

// ---------------------------------------------------------------------------
// MFMA flash attention v8 (causal): KEY-SPLIT pairs + T2 swizzle + T14.
// (structure unchanged from R8 -- verified)
// ---------------------------------------------------------------------------
__global__ __launch_bounds__(256)
void attn_mfma(const u16* __restrict__ qkv, const u16* __restrict__ VT,
               u16* __restrict__ out, float* __restrict__ partO,
               float* __restrict__ partML) {
    __shared__ u16 Ks[2][64 * 32];    // [kf d-chunk][key*32 + dL]  (swizzled)
    __shared__ u16 VsT[2][64 * 32];   // [kc key-chunk][d*32 + kL]  (swizzled)
    __shared__ u16 Ps[4][16 * 68];    // per-wave strip, reused by H then L

    const int tid  = threadIdx.x;
    const int lane = tid & 63;
    const int wv   = tid >> 6;

    const int bid  = blockIdx.x;
    const int idx  = bid >> 3;
    const int bh   = (bid & 7) * 4 + (idx >> 5);
    const int rem  = idx & 31;
    const int pr   = rem >> 1;
    const int role = rem & 1;
    const int qtH  = 31 - pr;
    const int qtL  = pr;
    const int h    = bh & (N_HEADS - 1);
    const int b    = bh >> 4;

    const int l15  = lane & 15;
    const int quad = lane >> 4;
    const int qsw  = quad ^ ((l15 >> 1) & 3);       // swizzled read chunk
    const int qw0H = qtH * 64 + wv * 16;

    const size_t vtb = (size_t)bh * D_K * S_LEN;
    u16* Psw = &Ps[wv][0];
    const int lr  = lane >> 2;
    const int csw = ((lane & 3) ^ ((lane >> 3) & 3)) * 8;  // swizzled src chunk

    auto STAGE = [&](int kts) {
        const int k0s = kts * 64;
#pragma unroll
        for (int kf = 0; kf < 2; kf++)
            gload_lds16(qkv + ((size_t)(b * S_LEN + k0s + wv * 16 + lr) * 3 + 1) * D_MODEL
                            + h * D_K + kf * 32 + csw,
                        &Ks[kf][(wv * 16) * 32]);
#pragma unroll
        for (int kc = 0; kc < 2; kc++)
            gload_lds16(VT + vtb + (size_t)(wv * 16 + lr) * S_LEN + k0s + kc * 32 + csw,
                        &VsT[kc][(wv * 16) * 32]);
    };

    ushort8 kreg[2], vreg[2];
    auto REGLOAD = [&](int kts) {
        const int k0s = kts * 64;
#pragma unroll
        for (int kf = 0; kf < 2; kf++)
            kreg[kf] = *(const ushort8*)&qkv[((size_t)(b * S_LEN + k0s + wv * 16 + lr) * 3 + 1) * D_MODEL
                                             + h * D_K + kf * 32 + csw];
#pragma unroll
        for (int kc = 0; kc < 2; kc++)
            vreg[kc] = *(const ushort8*)&VT[vtb + (size_t)(wv * 16 + lr) * S_LEN + k0s + kc * 32 + csw];
    };
    auto LDSW = [&]() {
#pragma unroll
        for (int kf = 0; kf < 2; kf++)
            *(ushort8*)&Ks[kf][(wv * 16) * 32 + lane * 8] = kreg[kf];
#pragma unroll
        for (int kc = 0; kc < 2; kc++)
            *(ushort8*)&VsT[kc][(wv * 16) * 32 + lane * 8] = vreg[kc];
    };

    // ---- H q-tile: role 0 -> kt in [0,16]; role 1 -> kt in [17, qtH] ----
    short8 qfH[2];
#pragma unroll
    for (int kf = 0; kf < 2; kf++)
        qfH[kf] = *(const short8*)&qkv[((size_t)(b * S_LEN + qw0H + l15) * 3 + 0) * D_MODEL
                                       + h * D_K + kf * 32 + quad * 8];
    f32x4 accH[4] = {};
    float mqH = -INFINITY, lqH = 0.f;

    const int kbeg = role ? 17 : 0;
    const int kend = role ? qtH : 16;
    if (kbeg <= kend) {
        STAGE(kbeg);
        __syncthreads();
        for (int kt = kbeg; kt <= kend; kt++) {
            const bool more = kt < kend;
            if (more) REGLOAD(kt + 1);
            attn_step(&Ks[0][0], &VsT[0][0], Psw, qfH, accH, mqH, lqH,
                      kt * 64, qw0H, kt == qtH, l15, quad, qsw);
            __syncthreads();
            if (more) { LDSW(); __syncthreads(); }
        }
    }

    // ---- write H partial (unnormalized, defer-max state, log2 domain) ----
    {
        const size_t unit = (size_t)(bh * 16 + (qtH - 16)) * 2 + role;
        float* Od = partO + unit * 4096 + (size_t)(wv * 16 + l15) * 64;
#pragma unroll
        for (int nj = 0; nj < 4; nj++)
            *(f32x4*)&Od[nj * 16 + quad * 4] = accH[nj];
        if (quad == 0) {
            float* ML = partML + unit * 128;
            ML[wv * 16 + l15]      = mqH;
            ML[64 + wv * 16 + l15] = lqH;
        }
    }

    if (!role) return;

    // ---- L q-tile (role 1 only): kt 0..qtL, direct output ----
    const int qw0L = qtL * 64 + wv * 16;
    short8 qfL[2];
#pragma unroll
    for (int kf = 0; kf < 2; kf++)
        qfL[kf] = *(const short8*)&qkv[((size_t)(b * S_LEN + qw0L + l15) * 3 + 0) * D_MODEL
                                       + h * D_K + kf * 32 + quad * 8];
    f32x4 accL[4] = {};
    float mqL = -INFINITY, lqL = 0.f;

    STAGE(0);
    __syncthreads();
    for (int kt = 0; kt <= qtL; kt++) {
        const bool more = kt < qtL;
        if (more) REGLOAD(kt + 1);
        attn_step(&Ks[0][0], &VsT[0][0], Psw, qfL, accL, mqL, lqL,
                  kt * 64, qw0L, kt == qtL, l15, quad, qsw);
        __syncthreads();
        if (more) { LDSW(); __syncthreads(); }
    }

    float invl = 1.f / lqL;
#pragma unroll
    for (int nj = 0; nj < 4; nj++) {
        ushort4 o;
        o.x = f2bf(accL[nj][0] * invl); o.y = f2bf(accL[nj][1] * invl);
        o.z = f2bf(accL[nj][2] * invl); o.w = f2bf(accL[nj][3] * invl);
        *(ushort4*)&out[(size_t)(b * S_LEN + qw0L + l15) * D_MODEL
                        + h * D_K + nj * 16 + quad * 4] = o;
    }
}

// ---------------------------------------------------------------------------
// Merge the two key-range partials of each H q-tile (log2 domain).
// ---------------------------------------------------------------------------
__global__ __launch_bounds__(256)
void attn_combine(const float* __restrict__ partO, const float* __restrict__ partML,
                  u16* __restrict__ out) {
    const int t16 = blockIdx.x & 15;
    const int bh  = blockIdx.x >> 4;
    const int h = bh & (N_HEADS - 1), b = bh >> 4;
    const int q0 = (t16 + 16) * 64;
    const int tid = threadIdx.x;
    const int q  = tid >> 2;
    const int d0 = (tid & 3) * 16;

    const size_t u0 = (size_t)(bh * 16 + t16) * 2;
    const float* O0 = partO + u0 * 4096;
    const float* O1 = O0 + 4096;
    const float* ML0 = partML + u0 * 128;
    const float* ML1 = ML0 + 128;

    float m0 = ML0[q], l0 = ML0[64 + q];
    float m1 = ML1[q], l1 = ML1[64 + q];
    float ms = fmaxf(m0, m1);
    float f0 = fast_exp2(m0 - ms), f1 = fast_exp2(m1 - ms);
    float inv = 1.f / (l0 * f0 + l1 * f1);
    f0 *= inv; f1 *= inv;
#pragma unroll
    for (int i = 0; i < 4; i++) {
        float4 a = *(const float4*)&O0[q * 64 + d0 + i * 4];
        float4 c = *(const float4*)&O1[q * 64 + d0 + i * 4];
        ushort4 o;
        o.x = f2bf(a.x * f0 + c.x * f1);
        o.y = f2bf(a.y * f0 + c.y * f1);
        o.z = f2bf(a.z * f0 + c.z * f1);
        o.w = f2bf(a.w * f0 + c.w * f1);
        *(ushort4*)&out[(size_t)(b * S_LEN + q0 + q) * D_MODEL + h * D_K + d0 + i * 4] = o;
    }
}

// ---------------------------------------------------------------------------
extern "C" void kernel_launch(void* const* d_in, const int* in_sizes, int n_in,
                              void* d_out, int out_size, void* d_ws, size_t ws_size,
                              hipStream_t stream) {
    const float* x    = (const float*)d_in[0];
    const int*   pos  = (const int*)d_in[1];
    const float* Wqkv = (const float*)d_in[2];
    const float* Wout = (const float*)d_in[3];
    float*       out  = (float*)d_out;

    const int M = B_SZ * S_LEN;   // 4096

    u16* qkvb = (u16*)d_ws;                            // 4096 x 3072
    u16* aob  = qkvb + (size_t)M * 3 * D_MODEL;        // 4096 x 1024
    u16* xb   = aob  + (size_t)M * D_MODEL;            // 4096 x 1024
    u16* wqb  = xb   + (size_t)M * D_MODEL;            // 3072 x 1024
    u16* wob  = wqb  + (size_t)3 * D_MODEL * D_MODEL;  // 1024 x 1024
    u16* vtb  = wob  + (size_t)D_MODEL * D_MODEL;      // 4096 x 1024
    float* partO  = (float*)(vtb + (size_t)M * D_MODEL);   // 1024 x 4096 f32
    float* partML = partO + (size_t)1024 * 4096;            // 1024 x 128 f32

    const int na4 = M * D_MODEL / 4;
    const int nb4 = 3 * D_MODEL * D_MODEL / 4;
    const int nc4 = D_MODEL * D_MODEL / 4;
    cast3_f32_bf16<<<(na4 + nb4 + nc4 + 255) / 256, 256, 0, stream>>>(
        x, xb, na4, Wqkv, wqb, nb4, Wout, wob, nc4);

    // gemm1 with fused RoPE + Q log2-scale epilogue
    gemm_qkv_rope<<<dim3(3 * D_MODEL / 128, M / 128), 256, 0, stream>>>(
        xb, wqb, qkvb, pos, M, 3 * D_MODEL, D_MODEL);

    // V transpose only (RoPE no longer a separate pass)
    vtrans<<<1024, 256, 0, stream>>>(qkvb, vtb);

    attn_mfma<<<1024, 256, 0, stream>>>(qkvb, vtb, aob, partO, partML);
    attn_combine<<<512, 256, 0, stream>>>(partO, partML, aob);

    gemm_bt_mfma_64r<<<dim3(D_MODEL / 128, M / 64), 256, 0, stream>>>(
        aob, wob, out, M, D_MODEL, D_MODEL);
}